// Round 1
// baseline (1033.907 us; speedup 1.0000x reference)
//
#include <hip/hip_runtime.h>
#include <hip/hip_bf16.h>

// Problem constants (from reference): B=2, S=4096, D=768, H=12, DH=64, W=256
#define BATCH 2
#define SEQ   4096
#define DMODEL 768
#define NHEAD 12
#define HDIM  64
#define WIN   256          // one-sided window
#define NBLK  16           // SEQ / 256 query blocks
#define MTOT  (BATCH*SEQ)  // 8192 tokens
#define NTOT  (3*DMODEL)   // 2304 fused output cols

// ---------------------------------------------------------------------------
// Fused QKV projection GEMM: A[8192,768] x {Wq|Wk|Wv}[768,768] (+bias, q/8)
// Output layout head-split: q/k/v[(b*H+h)*S + s][d]  (fp32)
// Tile: 128x128, BK=16, 256 threads, 8x8 microtile per thread.
// ---------------------------------------------------------------------------
__global__ __launch_bounds__(256) void qkv_gemm(
    const float* __restrict__ A,
    const float* __restrict__ Wq, const float* __restrict__ Wk, const float* __restrict__ Wv,
    const float* __restrict__ bq, const float* __restrict__ bk, const float* __restrict__ bv,
    float* __restrict__ qo, float* __restrict__ ko, float* __restrict__ vo)
{
    __shared__ float As[16][136];   // [k][m], +8 pad
    __shared__ float Bs[16][136];   // [k][n], +8 pad

    const int t  = threadIdx.x;
    const int tm = t & 15;          // 16 row groups
    const int tn = t >> 4;          // 16 col groups
    const int rowStart = blockIdx.y * 128;
    const int nGlob0   = blockIdx.x * 128;
    const int mat      = nGlob0 / DMODEL;          // 0=q 1=k 2=v (128 | 768 so uniform)
    const int nColBase = nGlob0 - mat * DMODEL;
    const float* W    = (mat == 0) ? Wq : (mat == 1) ? Wk : Wv;
    const float* bias = (mat == 0) ? bq : (mat == 1) ? bk : bv;
    float* outp       = (mat == 0) ? qo : (mat == 1) ? ko : vo;
    const float scl   = (mat == 0) ? 0.125f : 1.0f;

    float acc[8][8];
    #pragma unroll
    for (int i = 0; i < 8; i++)
        #pragma unroll
        for (int j = 0; j < 8; j++) acc[i][j] = 0.f;

    for (int k0 = 0; k0 < DMODEL; k0 += 16) {
        // --- stage A tile (transposed to [k][m]) ---
        #pragma unroll
        for (int i = 0; i < 2; i++) {
            int idx = t + i * 256;            // 0..511 float4 slots (128 rows x 4)
            int row = idx >> 2;
            int kc  = (idx & 3) << 2;
            float4 av = *(const float4*)(A + (size_t)(rowStart + row) * DMODEL + k0 + kc);
            As[kc + 0][row] = av.x;
            As[kc + 1][row] = av.y;
            As[kc + 2][row] = av.z;
            As[kc + 3][row] = av.w;
        }
        // --- stage B tile [k][n] ---
        #pragma unroll
        for (int i = 0; i < 2; i++) {
            int idx = t + i * 256;            // 0..511 float4 slots (16 k x 32)
            int kr  = idx >> 5;
            int nc  = (idx & 31) << 2;
            float4 bv4 = *(const float4*)(W + (size_t)(k0 + kr) * DMODEL + nColBase + nc);
            *(float4*)&Bs[kr][nc] = bv4;
        }
        __syncthreads();
        #pragma unroll
        for (int kk = 0; kk < 16; kk++) {
            float a[8], b[8];
            *(float4*)&a[0] = *(const float4*)&As[kk][tm * 8];
            *(float4*)&a[4] = *(const float4*)&As[kk][tm * 8 + 4];
            *(float4*)&b[0] = *(const float4*)&Bs[kk][tn * 8];
            *(float4*)&b[4] = *(const float4*)&Bs[kk][tn * 8 + 4];
            #pragma unroll
            for (int i = 0; i < 8; i++)
                #pragma unroll
                for (int j = 0; j < 8; j++)
                    acc[i][j] += a[i] * b[j];
        }
        __syncthreads();
    }

    // epilogue: bias, scale, scatter to head-split layout
    #pragma unroll
    for (int i = 0; i < 8; i++) {
        int token = rowStart + tm * 8 + i;
        int b = token >> 12;           // /4096
        int s = token & 4095;
        #pragma unroll
        for (int j = 0; j < 8; j++) {
            int ncol = nColBase + tn * 8 + j;
            int h = ncol >> 6, d = ncol & 63;
            float val = (acc[i][j] + bias[ncol]) * scl;
            outp[(((size_t)(b * NHEAD + h)) * SEQ + s) * HDIM + d] = val;
        }
    }
}

// ---------------------------------------------------------------------------
// Sliding-window attention. One block = (b, h, 256-query block), 256 threads,
// one query per thread. K/V streamed through LDS in 12 chunks of 64 rows.
// Defer-max online softmax; window/bounds/key-mask => score -1e9 (as ref).
// ---------------------------------------------------------------------------
__global__ __launch_bounds__(256) void attn_win(
    const float* __restrict__ Q, const float* __restrict__ Kt, const float* __restrict__ Vt,
    const float* __restrict__ amask, float* __restrict__ out)
{
    __shared__ float Ks[64][64];
    __shared__ float Vs[64][64];
    __shared__ float kmsk[64];

    const int t  = threadIdx.x;
    const int nb = blockIdx.x, h = blockIdx.y, b = blockIdx.z;
    const int i  = nb * 256 + t;                 // this thread's query index
    const size_t bh = (size_t)(b * NHEAD + h);

    float q[64], o[64];
    const float* qp = Q + (bh * SEQ + i) * HDIM;
    #pragma unroll
    for (int d4 = 0; d4 < 16; d4++)
        *(float4*)&q[d4 * 4] = *(const float4*)(qp + d4 * 4);
    #pragma unroll
    for (int d = 0; d < 64; d++) o[d] = 0.f;

    float m = -1e9f, l = 0.f;
    const bool qmasked = amask[(size_t)b * SEQ + i] < 0.f;

    for (int c = 0; c < 12; c++) {
        const int j0 = nb * 256 - WIN + c * 64;
        __syncthreads();   // previous chunk's compute done before overwrite
        #pragma unroll
        for (int i2 = 0; i2 < 4; i2++) {
            int idx = t + i2 * 256;              // 0..1023 float4 slots (64 x 16)
            int kk = idx >> 4;
            int d4 = (idx & 15) << 2;
            int j  = j0 + kk;
            float4 kv = make_float4(0.f, 0.f, 0.f, 0.f);
            float4 vv = make_float4(0.f, 0.f, 0.f, 0.f);
            if (j >= 0 && j < SEQ) {
                kv = *(const float4*)(Kt + (bh * SEQ + j) * HDIM + d4);
                vv = *(const float4*)(Vt + (bh * SEQ + j) * HDIM + d4);
            }
            *(float4*)&Ks[kk][d4] = kv;
            *(float4*)&Vs[kk][d4] = vv;
        }
        if (t < 64) {
            int j = j0 + t;
            kmsk[t] = (j >= 0 && j < SEQ) ? amask[(size_t)b * SEQ + j] : 0.f;
        }
        __syncthreads();

        for (int kk = 0; kk < 64; kk++) {
            const int j = j0 + kk;
            float s = 0.f;
            #pragma unroll
            for (int d4 = 0; d4 < 16; d4++) {
                float4 kv = *(const float4*)&Ks[kk][d4 * 4];
                s += q[d4*4+0]*kv.x + q[d4*4+1]*kv.y + q[d4*4+2]*kv.z + q[d4*4+3]*kv.w;
            }
            const int rel = j - i;
            const bool ok = (j >= 0) && (j < SEQ) && (rel <= WIN) && (rel >= -WIN)
                            && (kmsk[kk] >= 0.f);
            const float sc = ok ? s : -1e9f;
            float p;
            if (sc > m) {                         // rare: new running max
                const float f = __expf(m - sc);
                l *= f;
                #pragma unroll
                for (int d = 0; d < 64; d++) o[d] *= f;
                m = sc;
                p = 1.f;
            } else {
                p = __expf(sc - m);
            }
            l += p;
            #pragma unroll
            for (int d4 = 0; d4 < 16; d4++) {
                float4 vv = *(const float4*)&Vs[kk][d4 * 4];
                o[d4*4+0] += p * vv.x; o[d4*4+1] += p * vv.y;
                o[d4*4+2] += p * vv.z; o[d4*4+3] += p * vv.w;
            }
        }
    }

    const float inv = (qmasked || l <= 0.f) ? 0.f : 1.0f / l;
    float* op = out + ((size_t)b * SEQ + i) * DMODEL + h * HDIM;
    #pragma unroll
    for (int d4 = 0; d4 < 16; d4++) {
        float4 ov = make_float4(o[d4*4+0]*inv, o[d4*4+1]*inv, o[d4*4+2]*inv, o[d4*4+3]*inv);
        *(float4*)(op + d4 * 4) = ov;
    }
}

extern "C" void kernel_launch(void* const* d_in, const int* in_sizes, int n_in,
                              void* d_out, int out_size, void* d_ws, size_t ws_size,
                              hipStream_t stream) {
    const float* hs    = (const float*)d_in[0];
    const float* amask = (const float*)d_in[1];
    const float* Wq    = (const float*)d_in[2];
    const float* bq    = (const float*)d_in[3];
    const float* Wk    = (const float*)d_in[4];
    const float* bk    = (const float*)d_in[5];
    const float* Wv    = (const float*)d_in[6];
    const float* bv    = (const float*)d_in[7];
    float* outp = (float*)d_out;

    const size_t per = (size_t)BATCH * NHEAD * SEQ * HDIM;   // 6291456 floats
    float* qws = (float*)d_ws;
    float* kws = qws + per;
    float* vws = kws + per;

    qkv_gemm<<<dim3(NTOT / 128, MTOT / 128), 256, 0, stream>>>(
        hs, Wq, Wk, Wv, bq, bk, bv, qws, kws, vws);
    attn_win<<<dim3(NBLK, NHEAD, BATCH), 256, 0, stream>>>(
        qws, kws, vws, amask, outp);
}

// Round 2
// 176.980 us; speedup vs baseline: 5.8420x; 5.8420x over previous
//
#include <hip/hip_runtime.h>
#include <hip/hip_bf16.h>

#define BATCH 2
#define SEQ   4096
#define DM    768
#define NHEAD 12
#define HDIM  64
#define WIN   256

typedef unsigned short u16;
typedef __attribute__((ext_vector_type(8))) short bf16x8;
typedef __attribute__((ext_vector_type(4))) float f32x4;
typedef __attribute__((ext_vector_type(8))) unsigned short u16x8;
typedef __attribute__((ext_vector_type(4))) unsigned short u16x4;

__device__ __forceinline__ u16 f2bf(float x) {
    unsigned u = __builtin_bit_cast(unsigned, x);
    return (u16)((u + 0x7FFFu + ((u >> 16) & 1u)) >> 16);
}

// ---------------------------------------------------------------------------
// hidden fp32 -> bf16 (8 elems/thread)
// ---------------------------------------------------------------------------
__global__ __launch_bounds__(256) void aconv(const float* __restrict__ in, u16* __restrict__ outp) {
    size_t i = ((size_t)blockIdx.x * 256 + threadIdx.x) * 8;
    float4 a = *(const float4*)(in + i);
    float4 b = *(const float4*)(in + i + 4);
    u16x8 r;
    r[0] = f2bf(a.x); r[1] = f2bf(a.y); r[2] = f2bf(a.z); r[3] = f2bf(a.w);
    r[4] = f2bf(b.x); r[5] = f2bf(b.y); r[6] = f2bf(b.z); r[7] = f2bf(b.w);
    *(u16x8*)(outp + i) = r;
}

// ---------------------------------------------------------------------------
// W[k][n] fp32 -> Wt[mat][n][k] bf16  (32x32 LDS tiles)
// ---------------------------------------------------------------------------
__global__ __launch_bounds__(256) void wtrans(const float* __restrict__ Wq,
                                              const float* __restrict__ Wk,
                                              const float* __restrict__ Wv,
                                              u16* __restrict__ Wt) {
    __shared__ float tile[32][33];
    const int mat = blockIdx.z;
    const float* W = (mat == 0) ? Wq : (mat == 1) ? Wk : Wv;
    const int k0 = blockIdx.y * 32, n0 = blockIdx.x * 32;
    const int tx = threadIdx.x & 31, ty = threadIdx.x >> 5;   // ty 0..7
    #pragma unroll
    for (int i = 0; i < 32; i += 8)
        tile[ty + i][tx] = W[(size_t)(k0 + ty + i) * DM + n0 + tx];
    __syncthreads();
    #pragma unroll
    for (int i = 0; i < 32; i += 8)
        Wt[(size_t)mat * DM * DM + (size_t)(n0 + ty + i) * DM + k0 + tx] = f2bf(tile[tx][ty + i]);
}

// ---------------------------------------------------------------------------
// Fused QKV GEMM, bf16 MFMA 16x16x32. Tile 128x128, BK=32, 4 waves (2x2).
// q,k out: [bh][s][d] bf16 (q scaled 1/8); v out TRANSPOSED: [bh][d][s] bf16.
// ---------------------------------------------------------------------------
__global__ __launch_bounds__(256) void qkv_mfma(
    const u16* __restrict__ Abf, const u16* __restrict__ Wt,
    const float* __restrict__ bq, const float* __restrict__ bk, const float* __restrict__ bv,
    u16* __restrict__ qo, u16* __restrict__ ko, u16* __restrict__ vT)
{
    __shared__ u16 As[128][40];   // 80B rows: 16B-aligned, 2-way bank alias (free)
    __shared__ u16 Bs[128][40];

    const int t  = threadIdx.x;
    const int wv = t >> 6, ln = t & 63, lg = ln >> 4, lm = ln & 15;
    const int wr = wv >> 1, wc = wv & 1;
    const int rowStart = blockIdx.y * 128;
    const int nG = blockIdx.x * 128;
    const int mat = nG / DM;
    const int nColBase = nG - mat * DM;
    const float* bias = (mat == 0) ? bq : (mat == 1) ? bk : bv;
    const u16* Wm = Wt + (size_t)mat * DM * DM;

    f32x4 acc[4][4];
    #pragma unroll
    for (int i = 0; i < 4; i++)
        #pragma unroll
        for (int j = 0; j < 4; j++) acc[i][j] = (f32x4){0.f, 0.f, 0.f, 0.f};

    const int sm = t >> 1;            // staged row (A and B)
    const int sk = (t & 1) * 16;      // k offset (two 8-elem chunks)

    for (int k0 = 0; k0 < DM; k0 += 32) {
        u16x8 a0 = *(const u16x8*)(Abf + (size_t)(rowStart + sm) * DM + k0 + sk);
        u16x8 a1 = *(const u16x8*)(Abf + (size_t)(rowStart + sm) * DM + k0 + sk + 8);
        u16x8 b0 = *(const u16x8*)(Wm + (size_t)(nColBase + sm) * DM + k0 + sk);
        u16x8 b1 = *(const u16x8*)(Wm + (size_t)(nColBase + sm) * DM + k0 + sk + 8);
        __syncthreads();
        *(u16x8*)&As[sm][sk] = a0; *(u16x8*)&As[sm][sk + 8] = a1;
        *(u16x8*)&Bs[sm][sk] = b0; *(u16x8*)&Bs[sm][sk + 8] = b1;
        __syncthreads();
        bf16x8 af[4], bfr[4];
        #pragma unroll
        for (int mi = 0; mi < 4; mi++) af[mi]  = *(const bf16x8*)&As[wr * 64 + mi * 16 + lm][lg * 8];
        #pragma unroll
        for (int ni = 0; ni < 4; ni++) bfr[ni] = *(const bf16x8*)&Bs[wc * 64 + ni * 16 + lm][lg * 8];
        #pragma unroll
        for (int mi = 0; mi < 4; mi++)
            #pragma unroll
            for (int ni = 0; ni < 4; ni++)
                acc[mi][ni] = __builtin_amdgcn_mfma_f32_16x16x32_bf16(af[mi], bfr[ni], acc[mi][ni], 0, 0, 0);
    }

    // epilogue: C[row=token][col=feature]; col=lane&15, row=(lane>>4)*4+reg
    const int bb = rowStart >> 12;
    const int s0base = (rowStart & 4095) + wr * 64;
    const int col0 = nColBase + wc * 64;
    #pragma unroll
    for (int ni = 0; ni < 4; ni++) {
        const int col = col0 + ni * 16 + lm;
        const int h = col >> 6, d = col & 63;
        const float bsv = bias[col];
        #pragma unroll
        for (int mi = 0; mi < 4; mi++) {
            const int srow = s0base + mi * 16 + lg * 4;
            if (mat == 2) {
                u16x4 pk;
                #pragma unroll
                for (int r = 0; r < 4; r++) pk[r] = f2bf(acc[mi][ni][r] + bsv);
                *(u16x4*)(vT + ((size_t)((bb * NHEAD + h) * HDIM + d)) * SEQ + srow) = pk;
            } else {
                u16* dst = (mat == 0) ? qo : ko;
                const float scl = (mat == 0) ? 0.125f : 1.f;
                #pragma unroll
                for (int r = 0; r < 4; r++)
                    dst[((size_t)(bb * NHEAD + h) * SEQ + srow + r) * HDIM + d] =
                        f2bf((acc[mi][ni][r] + bsv) * scl);
            }
        }
    }
}

// ---------------------------------------------------------------------------
// MFMA flash attention. Block = (64-query tile, h, b), 4 waves x 16 q rows.
// 18 K-tiles of 32 keys (32-aligned -> fully in or fully out of [0,S)).
// ---------------------------------------------------------------------------
__global__ __launch_bounds__(256) void attn_mfma(
    const u16* __restrict__ Q, const u16* __restrict__ K,
    const u16* __restrict__ vT, const float* __restrict__ amask,
    float* __restrict__ out)
{
    __shared__ u16 Qs[64][72];     // 144B rows
    __shared__ u16 Ks[32][72];
    __shared__ u16 Vst[64][40];    // [d][j], 80B rows
    __shared__ u16 Pl[4][16][40];  // per-wave P tile [q][j]
    __shared__ float kmsk[32];

    const int t  = threadIdx.x;
    const int wv = t >> 6, ln = t & 63, lg = ln >> 4, lm = ln & 15;
    const int qb0 = blockIdx.x * 64;
    const int h = blockIdx.y, b = blockIdx.z;
    const size_t bh = (size_t)(b * NHEAD + h);

    // stage Q (64x64 bf16)
    {
        int s = t, i = s >> 3, d8 = (s & 7) * 8;
        *(u16x8*)&Qs[i][d8] = *(const u16x8*)(Q + (bh * SEQ + qb0 + i) * HDIM + d8);
        s = t + 256; i = s >> 3; d8 = (s & 7) * 8;
        *(u16x8*)&Qs[i][d8] = *(const u16x8*)(Q + (bh * SEQ + qb0 + i) * HDIM + d8);
    }
    __syncthreads();
    const bf16x8 qa0 = *(const bf16x8*)&Qs[wv * 16 + lm][lg * 8];
    const bf16x8 qa1 = *(const bf16x8*)&Qs[wv * 16 + lm][32 + lg * 8];

    f32x4 po[4];
    #pragma unroll
    for (int i = 0; i < 4; i++) po[i] = (f32x4){0.f, 0.f, 0.f, 0.f};
    float mrun[4], lrun[4];
    #pragma unroll
    for (int r = 0; r < 4; r++) { mrun[r] = -1e9f; lrun[r] = 0.f; }

    const int qi0 = qb0 + wv * 16 + lg * 4;

    for (int c = 0; c < 18; c++) {
        const int jt0 = qb0 - WIN + c * 32;
        if (jt0 < 0 || jt0 >= SEQ) continue;      // block-uniform
        __syncthreads();
        { int j = t >> 3, d8 = (t & 7) * 8;
          *(u16x8*)&Ks[j][d8] = *(const u16x8*)(K + (bh * SEQ + jt0 + j) * HDIM + d8); }
        { int d = t >> 2, j8 = (t & 3) * 8;
          *(u16x8*)&Vst[d][j8] = *(const u16x8*)(vT + (bh * HDIM + d) * SEQ + jt0 + j8); }
        if (t < 32) kmsk[t] = amask[(size_t)b * SEQ + jt0 + t];
        __syncthreads();

        // scores: C[q][j], 2 j-frags x 2 d-halves
        f32x4 s0v = (f32x4){0.f, 0.f, 0.f, 0.f}, s1v = (f32x4){0.f, 0.f, 0.f, 0.f};
        bf16x8 kb;
        kb = *(const bf16x8*)&Ks[lm][lg * 8];            s0v = __builtin_amdgcn_mfma_f32_16x16x32_bf16(qa0, kb, s0v, 0, 0, 0);
        kb = *(const bf16x8*)&Ks[lm][32 + lg * 8];       s0v = __builtin_amdgcn_mfma_f32_16x16x32_bf16(qa1, kb, s0v, 0, 0, 0);
        kb = *(const bf16x8*)&Ks[16 + lm][lg * 8];       s1v = __builtin_amdgcn_mfma_f32_16x16x32_bf16(qa0, kb, s1v, 0, 0, 0);
        kb = *(const bf16x8*)&Ks[16 + lm][32 + lg * 8];  s1v = __builtin_amdgcn_mfma_f32_16x16x32_bf16(qa1, kb, s1v, 0, 0, 0);

        const float km0 = kmsk[lm], km1 = kmsk[16 + lm];
        const int j0 = jt0 + lm, j1 = j0 + 16;
        float fs[4];
        #pragma unroll
        for (int r = 0; r < 4; r++) {
            const int qi = qi0 + r;
            float s0 = s0v[r], s1 = s1v[r];
            const bool a0 = (j0 - qi <= WIN) && (qi - j0 <= WIN) && (km0 >= 0.f);
            const bool a1 = (j1 - qi <= WIN) && (qi - j1 <= WIN) && (km1 >= 0.f);
            s0 = a0 ? s0 : -1e9f; s1 = a1 ? s1 : -1e9f;
            float tm = fmaxf(s0, s1);
            tm = fmaxf(tm, __shfl_xor(tm, 1)); tm = fmaxf(tm, __shfl_xor(tm, 2));
            tm = fmaxf(tm, __shfl_xor(tm, 4)); tm = fmaxf(tm, __shfl_xor(tm, 8));
            const float mnew = fmaxf(mrun[r], tm);
            const float f = __expf(mrun[r] - mnew);
            mrun[r] = mnew;
            const float p0 = a0 ? __expf(s0 - mnew) : 0.f;
            const float p1 = a1 ? __expf(s1 - mnew) : 0.f;
            float ps = p0 + p1;
            ps += __shfl_xor(ps, 1); ps += __shfl_xor(ps, 2);
            ps += __shfl_xor(ps, 4); ps += __shfl_xor(ps, 8);
            lrun[r] = lrun[r] * f + ps;
            fs[r] = f;
            Pl[wv][lg * 4 + r][lm] = f2bf(p0);
            Pl[wv][lg * 4 + r][16 + lm] = f2bf(p1);
        }
        asm volatile("" ::: "memory");   // keep P writes before P read
        const f32x4 ff = (f32x4){fs[0], fs[1], fs[2], fs[3]};
        #pragma unroll
        for (int df = 0; df < 4; df++) po[df] *= ff;
        const bf16x8 pa = *(const bf16x8*)&Pl[wv][lm][lg * 8];
        #pragma unroll
        for (int df = 0; df < 4; df++) {
            bf16x8 vb = *(const bf16x8*)&Vst[df * 16 + lm][lg * 8];
            po[df] = __builtin_amdgcn_mfma_f32_16x16x32_bf16(pa, vb, po[df], 0, 0, 0);
        }
    }

    #pragma unroll
    for (int r = 0; r < 4; r++) {
        const int qi = qi0 + r;
        const float l = lrun[r];
        const float inv = (l > 0.f && amask[(size_t)b * SEQ + qi] >= 0.f) ? 1.f / l : 0.f;
        float* op = out + ((size_t)b * SEQ + qi) * DM + h * HDIM;
        #pragma unroll
        for (int df = 0; df < 4; df++) op[df * 16 + lm] = po[df][r] * inv;
    }
}

extern "C" void kernel_launch(void* const* d_in, const int* in_sizes, int n_in,
                              void* d_out, int out_size, void* d_ws, size_t ws_size,
                              hipStream_t stream) {
    const float* hs    = (const float*)d_in[0];
    const float* amask = (const float*)d_in[1];
    const float* Wq    = (const float*)d_in[2];
    const float* bq    = (const float*)d_in[3];
    const float* Wk    = (const float*)d_in[4];
    const float* bk    = (const float*)d_in[5];
    const float* Wv    = (const float*)d_in[6];
    const float* bv    = (const float*)d_in[7];

    const size_t nA   = (size_t)BATCH * SEQ * DM;          // 6291456
    const size_t nW   = (size_t)3 * DM * DM;               // 1769472
    const size_t nQKV = (size_t)BATCH * NHEAD * SEQ * HDIM; // 6291456

    u16* Abf = (u16*)d_ws;
    u16* Wt  = Abf + nA;
    u16* qb  = Wt + nW;
    u16* kb  = qb + nQKV;
    u16* vT  = kb + nQKV;

    aconv<<<(int)(nA / (256 * 8)), 256, 0, stream>>>(hs, Abf);
    wtrans<<<dim3(DM / 32, DM / 32, 3), 256, 0, stream>>>(Wq, Wk, Wv, Wt);
    qkv_mfma<<<dim3(3 * DM / 128, BATCH * SEQ / 128), 256, 0, stream>>>(
        Abf, Wt, bq, bk, bv, qb, kb, vT);
    attn_mfma<<<dim3(SEQ / 64, NHEAD, BATCH), 256, 0, stream>>>(
        qb, kb, vT, amask, (float*)d_out);
}

// Round 3
// 128.492 us; speedup vs baseline: 8.0465x; 1.3774x over previous
//
#include <hip/hip_runtime.h>
#include <hip/hip_bf16.h>

#define BATCH 2
#define SEQ   4096
#define DM    768
#define NHEAD 12
#define HDIM  64
#define WIN   256

typedef unsigned short u16;
typedef unsigned int u32;
typedef __attribute__((ext_vector_type(8))) short bf16x8;
typedef __attribute__((ext_vector_type(4))) float f32x4;
typedef __attribute__((ext_vector_type(8))) unsigned short u16x8;
typedef __attribute__((ext_vector_type(4))) unsigned short u16x4;

__device__ __forceinline__ u16 f2bf(float x) {
    unsigned u = __builtin_bit_cast(unsigned, x);
    return (u16)((u + 0x7FFFu + ((u >> 16) & 1u)) >> 16);
}

// async global->LDS, 16B per lane; LDS dest must be wave-uniform base + lane*16
#define GLL16(g, l) __builtin_amdgcn_global_load_lds( \
    (const __attribute__((address_space(1))) u32*)(g), \
    (__attribute__((address_space(3))) u32*)(l), 16, 0, 0)

// ---------------------------------------------------------------------------
// hidden fp32 -> bf16
// ---------------------------------------------------------------------------
__global__ __launch_bounds__(256) void aconv(const float* __restrict__ in, u16* __restrict__ outp) {
    size_t i = ((size_t)blockIdx.x * 256 + threadIdx.x) * 8;
    float4 a = *(const float4*)(in + i);
    float4 b = *(const float4*)(in + i + 4);
    u16x8 r;
    r[0] = f2bf(a.x); r[1] = f2bf(a.y); r[2] = f2bf(a.z); r[3] = f2bf(a.w);
    r[4] = f2bf(b.x); r[5] = f2bf(b.y); r[6] = f2bf(b.z); r[7] = f2bf(b.w);
    *(u16x8*)(outp + i) = r;
}

// ---------------------------------------------------------------------------
// W[k][n] fp32 -> Wt[mat][n][k] bf16
// ---------------------------------------------------------------------------
__global__ __launch_bounds__(256) void wtrans(const float* __restrict__ Wq,
                                              const float* __restrict__ Wk,
                                              const float* __restrict__ Wv,
                                              u16* __restrict__ Wt) {
    __shared__ float tile[32][33];
    const int mat = blockIdx.z;
    const float* W = (mat == 0) ? Wq : (mat == 1) ? Wk : Wv;
    const int k0 = blockIdx.y * 32, n0 = blockIdx.x * 32;
    const int tx = threadIdx.x & 31, ty = threadIdx.x >> 5;
    #pragma unroll
    for (int i = 0; i < 32; i += 8)
        tile[ty + i][tx] = W[(size_t)(k0 + ty + i) * DM + n0 + tx];
    __syncthreads();
    #pragma unroll
    for (int i = 0; i < 32; i += 8)
        Wt[(size_t)mat * DM * DM + (size_t)(n0 + ty + i) * DM + k0 + tx] = f2bf(tile[tx][ty + i]);
}

// ---------------------------------------------------------------------------
// Fused QKV GEMM (m97 structure): 128x128 tile, BK=32, global_load_lds x16.
// q,k out: [bh][s][d] bf16 (q scaled 1/8); v out transposed [bh][d][s].
// ---------------------------------------------------------------------------
__global__ __launch_bounds__(256) void qkv_mfma(
    const u16* __restrict__ Abf, const u16* __restrict__ Wt,
    const float* __restrict__ bq, const float* __restrict__ bk, const float* __restrict__ bv,
    u16* __restrict__ qo, u16* __restrict__ ko, u16* __restrict__ vT)
{
    __shared__ u16 As[128][32];
    __shared__ u16 Bs[128][32];

    const int t  = threadIdx.x;
    const int wv = t >> 6, ln = t & 63, lg = ln >> 4, lm = ln & 15;
    const int wr = wv >> 1, wc = wv & 1;
    const int rowStart = blockIdx.y * 128;
    const int nG = blockIdx.x * 128;
    const int mat = nG / DM;
    const int nColBase = nG - mat * DM;
    const float* bias = (mat == 0) ? bq : (mat == 1) ? bk : bv;
    const u16* Wm = Wt + (size_t)mat * DM * DM;

    f32x4 acc[4][4];
    #pragma unroll
    for (int i = 0; i < 4; i++)
        #pragma unroll
        for (int j = 0; j < 4; j++) acc[i][j] = (f32x4){0.f, 0.f, 0.f, 0.f};

    // staging geometry: elem e = pass*2048 + wv*512 + ln*8 (LDS linear)
    const int srow0 = wv * 16 + (ln >> 2);        // row for pass 0
    const int scol  = (ln & 3) * 8;
    u16* ldsA = &As[0][0] + wv * 512 + ln * 8;
    u16* ldsB = &Bs[0][0] + wv * 512 + ln * 8;
    const u16* gA = Abf + (size_t)(rowStart + srow0) * DM + scol;
    const u16* gB = Wm  + (size_t)(nColBase + srow0) * DM + scol;

    for (int k0 = 0; k0 < DM; k0 += 32) {
        __syncthreads();                       // prev frag reads done
        GLL16(gA + k0, ldsA);
        GLL16(gA + (size_t)64 * DM + k0, ldsA + 2048);
        GLL16(gB + k0, ldsB);
        GLL16(gB + (size_t)64 * DM + k0, ldsB + 2048);
        __syncthreads();                       // compiler drains vmcnt here
        bf16x8 af[4], bfr[4];
        #pragma unroll
        for (int mi = 0; mi < 4; mi++) af[mi]  = *(const bf16x8*)&As[wr * 64 + mi * 16 + lm][lg * 8];
        #pragma unroll
        for (int ni = 0; ni < 4; ni++) bfr[ni] = *(const bf16x8*)&Bs[wc * 64 + ni * 16 + lm][lg * 8];
        #pragma unroll
        for (int mi = 0; mi < 4; mi++)
            #pragma unroll
            for (int ni = 0; ni < 4; ni++)
                acc[mi][ni] = __builtin_amdgcn_mfma_f32_16x16x32_bf16(af[mi], bfr[ni], acc[mi][ni], 0, 0, 0);
    }

    const int bb = rowStart >> 12;
    const int s0base = (rowStart & 4095) + wr * 64;
    const int col0 = nColBase + wc * 64;
    #pragma unroll
    for (int ni = 0; ni < 4; ni++) {
        const int col = col0 + ni * 16 + lm;
        const int h = col >> 6, d = col & 63;
        const float bsv = bias[col];
        #pragma unroll
        for (int mi = 0; mi < 4; mi++) {
            const int srow = s0base + mi * 16 + lg * 4;
            if (mat == 2) {
                u16x4 pk;
                #pragma unroll
                for (int r = 0; r < 4; r++) pk[r] = f2bf(acc[mi][ni][r] + bsv);
                *(u16x4*)(vT + ((size_t)((bb * NHEAD + h) * HDIM + d)) * SEQ + srow) = pk;
            } else {
                u16* dst = (mat == 0) ? qo : ko;
                const float scl = (mat == 0) ? 0.125f : 1.f;
                #pragma unroll
                for (int r = 0; r < 4; r++)
                    dst[((size_t)(bb * NHEAD + h) * SEQ + srow + r) * HDIM + d] =
                        f2bf((acc[mi][ni][r] + bsv) * scl);
            }
        }
    }
}

// ---------------------------------------------------------------------------
// MFMA flash attention v3: 64-key tiles, XOR-swizzled LDS, dbuf staging,
// interior fast path (7/9 tiles skip all mask math), packed bf16 cvt.
// Block = (64-q tile, h, b); 4 waves x 16 q rows.
// ---------------------------------------------------------------------------
__global__ __launch_bounds__(256) void attn_mfma(
    const u16* __restrict__ Q, const u16* __restrict__ K,
    const u16* __restrict__ vT, const float* __restrict__ amask,
    float* __restrict__ out)
{
    __shared__ u16 Qs[64][64];
    __shared__ u16 Ks[2][64][64];
    __shared__ u16 Vs[2][64][64];     // [d][j]
    __shared__ u16 Pl[4][16][64];     // per-wave P, swizzled
    __shared__ float kmsk[2][64];

    const int t  = threadIdx.x;
    const int wv = t >> 6, ln = t & 63, lg = ln >> 4, lm = ln & 15;
    const int lm7 = lm & 7;
    const int qb0 = blockIdx.x * 64;
    const int h = blockIdx.y, b = blockIdx.z;
    const size_t bh = (size_t)(b * NHEAD + h);

    // stage Q swizzled (chunk ^= row&7)
    #pragma unroll
    for (int p = 0; p < 2; p++) {
        int idx = t + p * 256;
        int row = idx >> 3, c = idx & 7;
        u16x8 v = *(const u16x8*)(Q + (bh * SEQ + qb0 + row) * HDIM + c * 8);
        *(u16x8*)&Qs[row][(c ^ (row & 7)) * 8] = v;
    }
    __syncthreads();
    const bf16x8 qa0 = *(const bf16x8*)&Qs[wv * 16 + lm][((lg) ^ lm7) * 8];
    const bf16x8 qa1 = *(const bf16x8*)&Qs[wv * 16 + lm][((4 + lg) ^ lm7) * 8];

    f32x4 po[4];
    #pragma unroll
    for (int i = 0; i < 4; i++) po[i] = (f32x4){0.f, 0.f, 0.f, 0.f};
    float mrun[4], lrun[4];
    #pragma unroll
    for (int r = 0; r < 4; r++) { mrun[r] = -1e9f; lrun[r] = 0.f; }
    const int qi0 = qb0 + wv * 16 + lg * 4;

    const int tlo = (4 - (qb0 >> 6)) > 0 ? (4 - (qb0 >> 6)) : 0;
    const int thi_raw = (SEQ + 192 - qb0) >> 6;
    const int thi = thi_raw < 8 ? thi_raw : 8;

    u16x8 kreg[2], vreg[2];
    float kmreg = 0.f;

    auto load_regs = [&](int tt) {
        const int jt0 = qb0 - WIN + tt * 64;
        #pragma unroll
        for (int i = 0; i < 2; i++) {
            int cid = t + i * 256;
            int row = cid >> 3, c = cid & 7;
            kreg[i] = *(const u16x8*)(K  + (bh * SEQ + jt0 + row) * HDIM + c * 8);
            vreg[i] = *(const u16x8*)(vT + (bh * HDIM + row) * SEQ + jt0 + c * 8);
        }
        if (t < 64) kmreg = amask[(size_t)b * SEQ + jt0 + t];
    };
    auto write_lds = [&](int buf) {
        #pragma unroll
        for (int i = 0; i < 2; i++) {
            int cid = t + i * 256;
            int row = cid >> 3, c = cid & 7;
            *(u16x8*)&Ks[buf][row][(c ^ (row & 7)) * 8] = kreg[i];
            *(u16x8*)&Vs[buf][row][(c ^ (row & 7)) * 8] = vreg[i];
        }
        if (t < 64) kmsk[buf][t] = kmreg;
    };

    load_regs(tlo);
    write_lds(0);
    __syncthreads();
    int cur = 0;

    for (int tt = tlo; tt <= thi; ++tt) {
        const int jt0 = qb0 - WIN + tt * 64;
        if (tt < thi) load_regs(tt + 1);

        // ---- QK^T: S[q][j], 4 j-frags x 2 d-halves ----
        f32x4 sv[4];
        #pragma unroll
        for (int jf = 0; jf < 4; jf++) sv[jf] = (f32x4){0.f, 0.f, 0.f, 0.f};
        __builtin_amdgcn_s_setprio(1);
        #pragma unroll
        for (int jf = 0; jf < 4; jf++) {
            const u16* kr = &Ks[cur][jf * 16 + lm][0];
            bf16x8 kb0 = *(const bf16x8*)(kr + (((lg) ^ lm7) << 3));
            bf16x8 kb1 = *(const bf16x8*)(kr + (((4 + lg) ^ lm7) << 3));
            sv[jf] = __builtin_amdgcn_mfma_f32_16x16x32_bf16(qa0, kb0, sv[jf], 0, 0, 0);
            sv[jf] = __builtin_amdgcn_mfma_f32_16x16x32_bf16(qa1, kb1, sv[jf], 0, 0, 0);
        }
        __builtin_amdgcn_s_setprio(0);

        const float kmv = kmsk[cur][ln];
        const bool anym = (__ballot(kmv < 0.f) != 0ULL);
        const bool fastp = (tt >= 1) && (tt <= 7) && !anym;
        if (!fastp) {
            #pragma unroll
            for (int jf = 0; jf < 4; jf++) {
                const float km = kmsk[cur][jf * 16 + lm];
                const int j = jt0 + jf * 16 + lm;
                #pragma unroll
                for (int r = 0; r < 4; r++) {
                    const int rel = j - (qi0 + r);
                    const bool ok = (rel <= WIN) && (rel >= -WIN) && (km >= 0.f);
                    sv[jf][r] = ok ? sv[jf][r] : -1e9f;
                }
            }
        }

        // ---- online softmax per q-row ----
        float fs[4];
        #pragma unroll
        for (int r = 0; r < 4; r++) {
            float mx = fmaxf(fmaxf(sv[0][r], sv[1][r]), fmaxf(sv[2][r], sv[3][r]));
            mx = fmaxf(mx, __shfl_xor(mx, 1));
            mx = fmaxf(mx, __shfl_xor(mx, 2));
            mx = fmaxf(mx, __shfl_xor(mx, 4));
            mx = fmaxf(mx, __shfl_xor(mx, 8));
            const float mnew = fmaxf(mrun[r], mx);
            const float f = __expf(mrun[r] - mnew);
            mrun[r] = mnew;
            const float p0 = sv[0][r] > -1e8f ? __expf(sv[0][r] - mnew) : 0.f;
            const float p1 = sv[1][r] > -1e8f ? __expf(sv[1][r] - mnew) : 0.f;
            const float p2 = sv[2][r] > -1e8f ? __expf(sv[2][r] - mnew) : 0.f;
            const float p3 = sv[3][r] > -1e8f ? __expf(sv[3][r] - mnew) : 0.f;
            float ps = (p0 + p1) + (p2 + p3);
            ps += __shfl_xor(ps, 1); ps += __shfl_xor(ps, 2);
            ps += __shfl_xor(ps, 4); ps += __shfl_xor(ps, 8);
            lrun[r] = lrun[r] * f + ps;
            fs[r] = f;
            u32 pk01, pk23;
            asm("v_cvt_pk_bf16_f32 %0, %1, %2" : "=v"(pk01) : "v"(p0), "v"(p1));
            asm("v_cvt_pk_bf16_f32 %0, %1, %2" : "=v"(pk23) : "v"(p2), "v"(p3));
            const int prow = lg * 4 + r, pr7 = prow & 7;
            const int cl = lm & 7, ch = lm >> 3;
            u16* pr = &Pl[wv][prow][0];
            pr[(((0 + ch) ^ pr7) << 3) + cl] = (u16)pk01;
            pr[(((2 + ch) ^ pr7) << 3) + cl] = (u16)(pk01 >> 16);
            pr[(((4 + ch) ^ pr7) << 3) + cl] = (u16)pk23;
            pr[(((6 + ch) ^ pr7) << 3) + cl] = (u16)(pk23 >> 16);
        }
        asm volatile("" ::: "memory");   // P writes before P reads

        { const f32x4 ff = (f32x4){fs[0], fs[1], fs[2], fs[3]};
          po[0] *= ff; po[1] *= ff; po[2] *= ff; po[3] *= ff; }

        const u16* pw = &Pl[wv][lm][0];
        const bf16x8 pa0 = *(const bf16x8*)(pw + (((lg) ^ lm7) << 3));
        const bf16x8 pa1 = *(const bf16x8*)(pw + (((4 + lg) ^ lm7) << 3));
        __builtin_amdgcn_s_setprio(1);
        #pragma unroll
        for (int df = 0; df < 4; df++) {
            const u16* vr = &Vs[cur][df * 16 + lm][0];
            bf16x8 vb0 = *(const bf16x8*)(vr + (((lg) ^ lm7) << 3));
            bf16x8 vb1 = *(const bf16x8*)(vr + (((4 + lg) ^ lm7) << 3));
            po[df] = __builtin_amdgcn_mfma_f32_16x16x32_bf16(pa0, vb0, po[df], 0, 0, 0);
            po[df] = __builtin_amdgcn_mfma_f32_16x16x32_bf16(pa1, vb1, po[df], 0, 0, 0);
        }
        __builtin_amdgcn_s_setprio(0);

        if (tt < thi) write_lds(cur ^ 1);
        __syncthreads();
        cur ^= 1;
    }

    #pragma unroll
    for (int r = 0; r < 4; r++) {
        const int qi = qi0 + r;
        const float l = lrun[r];
        const float inv = (l > 0.f && amask[(size_t)b * SEQ + qi] >= 0.f) ? 1.f / l : 0.f;
        float* op = out + ((size_t)b * SEQ + qi) * DM + h * HDIM;
        #pragma unroll
        for (int df = 0; df < 4; df++) op[df * 16 + lm] = po[df][r] * inv;
    }
}

extern "C" void kernel_launch(void* const* d_in, const int* in_sizes, int n_in,
                              void* d_out, int out_size, void* d_ws, size_t ws_size,
                              hipStream_t stream) {
    const float* hs    = (const float*)d_in[0];
    const float* amask = (const float*)d_in[1];
    const float* Wq    = (const float*)d_in[2];
    const float* bq    = (const float*)d_in[3];
    const float* Wk    = (const float*)d_in[4];
    const float* bk    = (const float*)d_in[5];
    const float* Wv    = (const float*)d_in[6];
    const float* bv    = (const float*)d_in[7];

    const size_t nA   = (size_t)BATCH * SEQ * DM;
    const size_t nW   = (size_t)3 * DM * DM;
    const size_t nQKV = (size_t)BATCH * NHEAD * SEQ * HDIM;

    u16* Abf = (u16*)d_ws;
    u16* Wt  = Abf + nA;
    u16* qb  = Wt + nW;
    u16* kb  = qb + nQKV;
    u16* vT  = kb + nQKV;

    aconv<<<(int)(nA / (256 * 8)), 256, 0, stream>>>(hs, Abf);
    wtrans<<<dim3(DM / 32, DM / 32, 3), 256, 0, stream>>>(Wq, Wk, Wv, Wt);
    qkv_mfma<<<dim3(3 * DM / 128, BATCH * SEQ / 128), 256, 0, stream>>>(
        Abf, Wt, bq, bk, bv, qb, kb, vT);
    attn_mfma<<<dim3(SEQ / 64, NHEAD, BATCH), 256, 0, stream>>>(
        qb, kb, vT, amask, (float*)d_out);
}

// Round 4
// 118.659 us; speedup vs baseline: 8.7133x; 1.0829x over previous
//
#include <hip/hip_runtime.h>
#include <hip/hip_bf16.h>

#define BATCH 2
#define SEQ   4096
#define DM    768
#define NHEAD 12
#define HDIM  64
#define WIN   256

typedef unsigned short u16;
typedef unsigned int u32;
typedef __attribute__((ext_vector_type(8))) short bf16x8;
typedef __attribute__((ext_vector_type(4))) float f32x4;
typedef __attribute__((ext_vector_type(8))) unsigned short u16x8;
typedef __attribute__((ext_vector_type(4))) unsigned short u16x4;

__device__ __forceinline__ u16 f2bf(float x) {
    unsigned u = __builtin_bit_cast(unsigned, x);
    return (u16)((u + 0x7FFFu + ((u >> 16) & 1u)) >> 16);
}

// async global->LDS, 16B per lane; LDS dest must be wave-uniform base + lane*16
#define GLL16(g, l) __builtin_amdgcn_global_load_lds( \
    (const __attribute__((address_space(1))) u32*)(g), \
    (__attribute__((address_space(3))) u32*)(l), 16, 0, 0)

// ---------------------------------------------------------------------------
// prep: [blocks 0..3071] hidden fp32 -> bf16 ; [3072..4799] W -> Wt[mat][n][k]
// ---------------------------------------------------------------------------
__global__ __launch_bounds__(256) void prep(
    const float* __restrict__ in, u16* __restrict__ Abf,
    const float* __restrict__ Wq, const float* __restrict__ Wk,
    const float* __restrict__ Wv, u16* __restrict__ Wt)
{
    __shared__ float tile[32][33];
    const int bid = blockIdx.x;
    if (bid < 3072) {
        size_t i = ((size_t)bid * 256 + threadIdx.x) * 8;
        float4 a = *(const float4*)(in + i);
        float4 b = *(const float4*)(in + i + 4);
        u16x8 r;
        r[0] = f2bf(a.x); r[1] = f2bf(a.y); r[2] = f2bf(a.z); r[3] = f2bf(a.w);
        r[4] = f2bf(b.x); r[5] = f2bf(b.y); r[6] = f2bf(b.z); r[7] = f2bf(b.w);
        *(u16x8*)(Abf + i) = r;
    } else {
        const int wb = bid - 3072;
        const int mat = wb / 576;
        const int rem = wb - mat * 576;
        const int k0 = (rem / 24) * 32, n0 = (rem % 24) * 32;
        const float* W = (mat == 0) ? Wq : (mat == 1) ? Wk : Wv;
        const int tx = threadIdx.x & 31, ty = threadIdx.x >> 5;
        #pragma unroll
        for (int i = 0; i < 32; i += 8)
            tile[ty + i][tx] = W[(size_t)(k0 + ty + i) * DM + n0 + tx];
        __syncthreads();
        #pragma unroll
        for (int i = 0; i < 32; i += 8)
            Wt[(size_t)mat * DM * DM + (size_t)(n0 + ty + i) * DM + k0 + tx] = f2bf(tile[tx][ty + i]);
    }
}

// ---------------------------------------------------------------------------
// Fused QKV GEMM: 128x128 tile, BK=32, double-buffered global_load_lds,
// prefetch-before-compute, ONE barrier per K-iter (minimum 2-phase recipe).
// q,k out: [bh][s][d] bf16 (q scaled 1/8); v out transposed [bh][d][s].
// ---------------------------------------------------------------------------
__global__ __launch_bounds__(256) void qkv_mfma(
    const u16* __restrict__ Abf, const u16* __restrict__ Wt,
    const float* __restrict__ bq, const float* __restrict__ bk, const float* __restrict__ bv,
    u16* __restrict__ qo, u16* __restrict__ ko, u16* __restrict__ vT)
{
    __shared__ u16 As[2][128][32];
    __shared__ u16 Bs[2][128][32];

    const int t  = threadIdx.x;
    const int wv = t >> 6, ln = t & 63, lg = ln >> 4, lm = ln & 15;
    const int wr = wv >> 1, wc = wv & 1;
    const int rowStart = blockIdx.y * 128;
    const int nG = blockIdx.x * 128;
    const int mat = nG / DM;
    const int nColBase = nG - mat * DM;
    const float* bias = (mat == 0) ? bq : (mat == 1) ? bk : bv;
    const u16* Wm = Wt + (size_t)mat * DM * DM;

    f32x4 acc[4][4];
    #pragma unroll
    for (int i = 0; i < 4; i++)
        #pragma unroll
        for (int j = 0; j < 4; j++) acc[i][j] = (f32x4){0.f, 0.f, 0.f, 0.f};

    // staging geometry: elem = wv*512 + ln*8 within a [128][32] buffer
    const int srow0 = wv * 16 + (ln >> 2);
    const int scol  = (ln & 3) * 8;
    u16* ldsA0 = &As[0][0][0] + wv * 512 + ln * 8;
    u16* ldsB0 = &Bs[0][0][0] + wv * 512 + ln * 8;
    const u16* gA = Abf + (size_t)(rowStart + srow0) * DM + scol;
    const u16* gB = Wm  + (size_t)(nColBase + srow0) * DM + scol;

    #define STAGE(buf, k0) do { \
        u16* la_ = ldsA0 + (buf) * 4096; \
        u16* lb_ = ldsB0 + (buf) * 4096; \
        GLL16(gA + (k0), la_); \
        GLL16(gA + (size_t)64 * DM + (k0), la_ + 2048); \
        GLL16(gB + (k0), lb_); \
        GLL16(gB + (size_t)64 * DM + (k0), lb_ + 2048); \
    } while (0)

    STAGE(0, 0);
    __syncthreads();                    // drain prologue stage
    int cur = 0;

    for (int it = 0; it < 24; ++it) {
        const int k0 = it * 32;
        if (it < 23) STAGE(cur ^ 1, k0 + 32);   // issue next tile early
        bf16x8 af[4], bfr[4];
        #pragma unroll
        for (int mi = 0; mi < 4; mi++) af[mi]  = *(const bf16x8*)&As[cur][wr * 64 + mi * 16 + lm][lg * 8];
        #pragma unroll
        for (int ni = 0; ni < 4; ni++) bfr[ni] = *(const bf16x8*)&Bs[cur][wc * 64 + ni * 16 + lm][lg * 8];
        __builtin_amdgcn_s_setprio(1);
        #pragma unroll
        for (int mi = 0; mi < 4; mi++)
            #pragma unroll
            for (int ni = 0; ni < 4; ni++)
                acc[mi][ni] = __builtin_amdgcn_mfma_f32_16x16x32_bf16(af[mi], bfr[ni], acc[mi][ni], 0, 0, 0);
        __builtin_amdgcn_s_setprio(0);
        __syncthreads();               // drains vmcnt(0): next tile ready
        cur ^= 1;
    }

    const int bb = rowStart >> 12;
    const int s0base = (rowStart & 4095) + wr * 64;
    const int col0 = nColBase + wc * 64;
    #pragma unroll
    for (int ni = 0; ni < 4; ni++) {
        const int col = col0 + ni * 16 + lm;
        const int h = col >> 6, d = col & 63;
        const float bsv = bias[col];
        #pragma unroll
        for (int mi = 0; mi < 4; mi++) {
            const int srow = s0base + mi * 16 + lg * 4;
            if (mat == 2) {
                u16x4 pk;
                #pragma unroll
                for (int r = 0; r < 4; r++) pk[r] = f2bf(acc[mi][ni][r] + bsv);
                *(u16x4*)(vT + ((size_t)((bb * NHEAD + h) * HDIM + d)) * SEQ + srow) = pk;
            } else {
                u16* dst = (mat == 0) ? qo : ko;
                const float scl = (mat == 0) ? 0.125f : 1.f;
                #pragma unroll
                for (int r = 0; r < 4; r++)
                    dst[((size_t)(bb * NHEAD + h) * SEQ + srow + r) * HDIM + d] =
                        f2bf((acc[mi][ni][r] + bsv) * scl);
            }
        }
    }
}

// ---------------------------------------------------------------------------
// MFMA flash attention: 64-key tiles, XOR-swizzled LDS, dbuf staging,
// interior fast path, packed bf16 cvt. Block = (64-q tile, h, b).
// ---------------------------------------------------------------------------
__global__ __launch_bounds__(256) void attn_mfma(
    const u16* __restrict__ Q, const u16* __restrict__ K,
    const u16* __restrict__ vT, const float* __restrict__ amask,
    float* __restrict__ out)
{
    __shared__ u16 Qs[64][64];
    __shared__ u16 Ks[2][64][64];
    __shared__ u16 Vs[2][64][64];     // [d][j]
    __shared__ u16 Pl[4][16][64];
    __shared__ float kmsk[2][64];

    const int t  = threadIdx.x;
    const int wv = t >> 6, ln = t & 63, lg = ln >> 4, lm = ln & 15;
    const int lm7 = lm & 7;
    const int qb0 = blockIdx.x * 64;
    const int h = blockIdx.y, b = blockIdx.z;
    const size_t bh = (size_t)(b * NHEAD + h);

    #pragma unroll
    for (int p = 0; p < 2; p++) {
        int idx = t + p * 256;
        int row = idx >> 3, c = idx & 7;
        u16x8 v = *(const u16x8*)(Q + (bh * SEQ + qb0 + row) * HDIM + c * 8);
        *(u16x8*)&Qs[row][(c ^ (row & 7)) * 8] = v;
    }
    __syncthreads();
    const bf16x8 qa0 = *(const bf16x8*)&Qs[wv * 16 + lm][((lg) ^ lm7) * 8];
    const bf16x8 qa1 = *(const bf16x8*)&Qs[wv * 16 + lm][((4 + lg) ^ lm7) * 8];

    f32x4 po[4];
    #pragma unroll
    for (int i = 0; i < 4; i++) po[i] = (f32x4){0.f, 0.f, 0.f, 0.f};
    float mrun[4], lrun[4];
    #pragma unroll
    for (int r = 0; r < 4; r++) { mrun[r] = -1e9f; lrun[r] = 0.f; }
    const int qi0 = qb0 + wv * 16 + lg * 4;

    const int tlo = (4 - (qb0 >> 6)) > 0 ? (4 - (qb0 >> 6)) : 0;
    const int thi_raw = (SEQ + 192 - qb0) >> 6;
    const int thi = thi_raw < 8 ? thi_raw : 8;

    u16x8 kreg[2], vreg[2];
    float kmreg = 0.f;

    auto load_regs = [&](int tt) {
        const int jt0 = qb0 - WIN + tt * 64;
        #pragma unroll
        for (int i = 0; i < 2; i++) {
            int cid = t + i * 256;
            int row = cid >> 3, c = cid & 7;
            kreg[i] = *(const u16x8*)(K  + (bh * SEQ + jt0 + row) * HDIM + c * 8);
            vreg[i] = *(const u16x8*)(vT + (bh * HDIM + row) * SEQ + jt0 + c * 8);
        }
        if (t < 64) kmreg = amask[(size_t)b * SEQ + jt0 + t];
    };
    auto write_lds = [&](int buf) {
        #pragma unroll
        for (int i = 0; i < 2; i++) {
            int cid = t + i * 256;
            int row = cid >> 3, c = cid & 7;
            *(u16x8*)&Ks[buf][row][(c ^ (row & 7)) * 8] = kreg[i];
            *(u16x8*)&Vs[buf][row][(c ^ (row & 7)) * 8] = vreg[i];
        }
        if (t < 64) kmsk[buf][t] = kmreg;
    };

    load_regs(tlo);
    write_lds(0);
    __syncthreads();
    int cur = 0;

    for (int tt = tlo; tt <= thi; ++tt) {
        const int jt0 = qb0 - WIN + tt * 64;
        if (tt < thi) load_regs(tt + 1);

        f32x4 sv[4];
        #pragma unroll
        for (int jf = 0; jf < 4; jf++) sv[jf] = (f32x4){0.f, 0.f, 0.f, 0.f};
        __builtin_amdgcn_s_setprio(1);
        #pragma unroll
        for (int jf = 0; jf < 4; jf++) {
            const u16* kr = &Ks[cur][jf * 16 + lm][0];
            bf16x8 kb0 = *(const bf16x8*)(kr + (((lg) ^ lm7) << 3));
            bf16x8 kb1 = *(const bf16x8*)(kr + (((4 + lg) ^ lm7) << 3));
            sv[jf] = __builtin_amdgcn_mfma_f32_16x16x32_bf16(qa0, kb0, sv[jf], 0, 0, 0);
            sv[jf] = __builtin_amdgcn_mfma_f32_16x16x32_bf16(qa1, kb1, sv[jf], 0, 0, 0);
        }
        __builtin_amdgcn_s_setprio(0);

        const float kmv = kmsk[cur][ln];
        const bool anym = (__ballot(kmv < 0.f) != 0ULL);
        const bool fastp = (tt >= 1) && (tt <= 7) && !anym;
        if (!fastp) {
            #pragma unroll
            for (int jf = 0; jf < 4; jf++) {
                const float km = kmsk[cur][jf * 16 + lm];
                const int j = jt0 + jf * 16 + lm;
                #pragma unroll
                for (int r = 0; r < 4; r++) {
                    const int rel = j - (qi0 + r);
                    const bool ok = (rel <= WIN) && (rel >= -WIN) && (km >= 0.f);
                    sv[jf][r] = ok ? sv[jf][r] : -1e9f;
                }
            }
        }

        float fs[4];
        #pragma unroll
        for (int r = 0; r < 4; r++) {
            float mx = fmaxf(fmaxf(sv[0][r], sv[1][r]), fmaxf(sv[2][r], sv[3][r]));
            mx = fmaxf(mx, __shfl_xor(mx, 1));
            mx = fmaxf(mx, __shfl_xor(mx, 2));
            mx = fmaxf(mx, __shfl_xor(mx, 4));
            mx = fmaxf(mx, __shfl_xor(mx, 8));
            const float mnew = fmaxf(mrun[r], mx);
            const float f = __expf(mrun[r] - mnew);
            mrun[r] = mnew;
            const float p0 = sv[0][r] > -1e8f ? __expf(sv[0][r] - mnew) : 0.f;
            const float p1 = sv[1][r] > -1e8f ? __expf(sv[1][r] - mnew) : 0.f;
            const float p2 = sv[2][r] > -1e8f ? __expf(sv[2][r] - mnew) : 0.f;
            const float p3 = sv[3][r] > -1e8f ? __expf(sv[3][r] - mnew) : 0.f;
            float ps = (p0 + p1) + (p2 + p3);
            ps += __shfl_xor(ps, 1); ps += __shfl_xor(ps, 2);
            ps += __shfl_xor(ps, 4); ps += __shfl_xor(ps, 8);
            lrun[r] = lrun[r] * f + ps;
            fs[r] = f;
            u32 pk01, pk23;
            asm("v_cvt_pk_bf16_f32 %0, %1, %2" : "=v"(pk01) : "v"(p0), "v"(p1));
            asm("v_cvt_pk_bf16_f32 %0, %1, %2" : "=v"(pk23) : "v"(p2), "v"(p3));
            const int prow = lg * 4 + r, pr7 = prow & 7;
            const int cl = lm & 7, ch = lm >> 3;
            u16* pr = &Pl[wv][prow][0];
            pr[(((0 + ch) ^ pr7) << 3) + cl] = (u16)pk01;
            pr[(((2 + ch) ^ pr7) << 3) + cl] = (u16)(pk01 >> 16);
            pr[(((4 + ch) ^ pr7) << 3) + cl] = (u16)pk23;
            pr[(((6 + ch) ^ pr7) << 3) + cl] = (u16)(pk23 >> 16);
        }
        asm volatile("" ::: "memory");

        { const f32x4 ff = (f32x4){fs[0], fs[1], fs[2], fs[3]};
          po[0] *= ff; po[1] *= ff; po[2] *= ff; po[3] *= ff; }

        const u16* pw = &Pl[wv][lm][0];
        const bf16x8 pa0 = *(const bf16x8*)(pw + (((lg) ^ lm7) << 3));
        const bf16x8 pa1 = *(const bf16x8*)(pw + (((4 + lg) ^ lm7) << 3));
        __builtin_amdgcn_s_setprio(1);
        #pragma unroll
        for (int df = 0; df < 4; df++) {
            const u16* vr = &Vs[cur][df * 16 + lm][0];
            bf16x8 vb0 = *(const bf16x8*)(vr + (((lg) ^ lm7) << 3));
            bf16x8 vb1 = *(const bf16x8*)(vr + (((4 + lg) ^ lm7) << 3));
            po[df] = __builtin_amdgcn_mfma_f32_16x16x32_bf16(pa0, vb0, po[df], 0, 0, 0);
            po[df] = __builtin_amdgcn_mfma_f32_16x16x32_bf16(pa1, vb1, po[df], 0, 0, 0);
        }
        __builtin_amdgcn_s_setprio(0);

        if (tt < thi) write_lds(cur ^ 1);
        __syncthreads();
        cur ^= 1;
    }

    #pragma unroll
    for (int r = 0; r < 4; r++) {
        const int qi = qi0 + r;
        const float l = lrun[r];
        const float inv = (l > 0.f && amask[(size_t)b * SEQ + qi] >= 0.f) ? 1.f / l : 0.f;
        float* op = out + ((size_t)b * SEQ + qi) * DM + h * HDIM;
        #pragma unroll
        for (int df = 0; df < 4; df++) op[df * 16 + lm] = po[df][r] * inv;
    }
}

extern "C" void kernel_launch(void* const* d_in, const int* in_sizes, int n_in,
                              void* d_out, int out_size, void* d_ws, size_t ws_size,
                              hipStream_t stream) {
    const float* hs    = (const float*)d_in[0];
    const float* amask = (const float*)d_in[1];
    const float* Wq    = (const float*)d_in[2];
    const float* bq    = (const float*)d_in[3];
    const float* Wk    = (const float*)d_in[4];
    const float* bk    = (const float*)d_in[5];
    const float* Wv    = (const float*)d_in[6];
    const float* bv    = (const float*)d_in[7];

    const size_t nA   = (size_t)BATCH * SEQ * DM;
    const size_t nW   = (size_t)3 * DM * DM;
    const size_t nQKV = (size_t)BATCH * NHEAD * SEQ * HDIM;

    u16* Abf = (u16*)d_ws;
    u16* Wt  = Abf + nA;
    u16* qb  = Wt + nW;
    u16* kb  = qb + nQKV;
    u16* vT  = kb + nQKV;

    prep<<<4800, 256, 0, stream>>>(hs, Abf, Wq, Wk, Wv, Wt);
    qkv_mfma<<<dim3(3 * DM / 128, BATCH * SEQ / 128), 256, 0, stream>>>(
        Abf, Wt, bq, bk, bv, qb, kb, vT);
    attn_mfma<<<dim3(SEQ / 64, NHEAD, BATCH), 256, 0, stream>>>(
        qb, kb, vT, amask, (float*)d_out);
}

// Round 5
// 102.162 us; speedup vs baseline: 10.1203x; 1.1615x over previous
//
#include <hip/hip_runtime.h>
#include <hip/hip_bf16.h>

#define BATCH 2
#define SEQ   4096
#define DM    768
#define NHEAD 12
#define HDIM  64
#define WIN   256

typedef unsigned short u16;
typedef unsigned int u32;
typedef __attribute__((ext_vector_type(8))) short bf16x8;
typedef __attribute__((ext_vector_type(4))) float f32x4;
typedef __attribute__((ext_vector_type(8))) unsigned short u16x8;
typedef __attribute__((ext_vector_type(4))) unsigned short u16x4;
typedef __attribute__((ext_vector_type(2))) unsigned int u32x2;

__device__ __forceinline__ u16 f2bf(float x) {
    unsigned u = __builtin_bit_cast(unsigned, x);
    return (u16)((u + 0x7FFFu + ((u >> 16) & 1u)) >> 16);
}

// async global->LDS, 16B per lane; LDS dest must be wave-uniform base + lane*16
#define GLL16(g, l) __builtin_amdgcn_global_load_lds( \
    (const __attribute__((address_space(1))) u32*)(g), \
    (__attribute__((address_space(3))) u32*)(l), 16, 0, 0)

// ---------------------------------------------------------------------------
// prep: [blocks 0..3071] hidden fp32 -> bf16 ; [3072..4799] W -> Wt[mat][n][k]
// ---------------------------------------------------------------------------
__global__ __launch_bounds__(256) void prep(
    const float* __restrict__ in, u16* __restrict__ Abf,
    const float* __restrict__ Wq, const float* __restrict__ Wk,
    const float* __restrict__ Wv, u16* __restrict__ Wt)
{
    __shared__ float tile[32][33];
    const int bid = blockIdx.x;
    if (bid < 3072) {
        size_t i = ((size_t)bid * 256 + threadIdx.x) * 8;
        float4 a = *(const float4*)(in + i);
        float4 b = *(const float4*)(in + i + 4);
        u16x8 r;
        r[0] = f2bf(a.x); r[1] = f2bf(a.y); r[2] = f2bf(a.z); r[3] = f2bf(a.w);
        r[4] = f2bf(b.x); r[5] = f2bf(b.y); r[6] = f2bf(b.z); r[7] = f2bf(b.w);
        *(u16x8*)(Abf + i) = r;
    } else {
        const int wb = bid - 3072;
        const int mat = wb / 576;
        const int rem = wb - mat * 576;
        const int k0 = (rem / 24) * 32, n0 = (rem % 24) * 32;
        const float* W = (mat == 0) ? Wq : (mat == 1) ? Wk : Wv;
        const int tx = threadIdx.x & 31, ty = threadIdx.x >> 5;
        #pragma unroll
        for (int i = 0; i < 32; i += 8)
            tile[ty + i][tx] = W[(size_t)(k0 + ty + i) * DM + n0 + tx];
        __syncthreads();
        #pragma unroll
        for (int i = 0; i < 32; i += 8)
            Wt[(size_t)mat * DM * DM + (size_t)(n0 + ty + i) * DM + k0 + tx] = f2bf(tile[tx][ty + i]);
    }
}

// ---------------------------------------------------------------------------
// Fused QKV GEMM: 128x128 tile, BK=32, dbuf global_load_lds, 1 barrier/iter,
// XCD-chunked block swizzle. q scaled by (1/8)*log2(e) so attn uses exp2.
// ---------------------------------------------------------------------------
__global__ __launch_bounds__(256) void qkv_mfma(
    const u16* __restrict__ Abf, const u16* __restrict__ Wt,
    const float* __restrict__ bq, const float* __restrict__ bk, const float* __restrict__ bv,
    u16* __restrict__ qo, u16* __restrict__ ko, u16* __restrict__ vT)
{
    __shared__ u16 As[2][128][32];
    __shared__ u16 Bs[2][128][32];

    const int t  = threadIdx.x;
    const int wv = t >> 6, ln = t & 63, lg = ln >> 4, lm = ln & 15;
    const int wr = wv >> 1, wc = wv & 1;

    // XCD-chunked swizzle: 1152 blocks, XCD c gets row-stripes [c*8, c*8+8)
    const int id  = blockIdx.x + 18 * blockIdx.y;
    const int nid = (id & 7) * 144 + (id >> 3);
    const int bx  = nid % 18, by = nid / 18;

    const int rowStart = by * 128;
    const int nG = bx * 128;
    const int mat = nG / DM;
    const int nColBase = nG - mat * DM;
    const float* bias = (mat == 0) ? bq : (mat == 1) ? bk : bv;
    const u16* Wm = Wt + (size_t)mat * DM * DM;

    f32x4 acc[4][4];
    #pragma unroll
    for (int i = 0; i < 4; i++)
        #pragma unroll
        for (int j = 0; j < 4; j++) acc[i][j] = (f32x4){0.f, 0.f, 0.f, 0.f};

    const int srow0 = wv * 16 + (ln >> 2);
    const int scol  = (ln & 3) * 8;
    u16* ldsA0 = &As[0][0][0] + wv * 512 + ln * 8;
    u16* ldsB0 = &Bs[0][0][0] + wv * 512 + ln * 8;
    const u16* gA = Abf + (size_t)(rowStart + srow0) * DM + scol;
    const u16* gB = Wm  + (size_t)(nColBase + srow0) * DM + scol;

    #define STAGE(buf, k0) do { \
        u16* la_ = ldsA0 + (buf) * 4096; \
        u16* lb_ = ldsB0 + (buf) * 4096; \
        GLL16(gA + (k0), la_); \
        GLL16(gA + (size_t)64 * DM + (k0), la_ + 2048); \
        GLL16(gB + (k0), lb_); \
        GLL16(gB + (size_t)64 * DM + (k0), lb_ + 2048); \
    } while (0)

    STAGE(0, 0);
    __syncthreads();
    int cur = 0;

    for (int it = 0; it < 24; ++it) {
        const int k0 = it * 32;
        if (it < 23) STAGE(cur ^ 1, k0 + 32);
        bf16x8 af[4], bfr[4];
        #pragma unroll
        for (int mi = 0; mi < 4; mi++) af[mi]  = *(const bf16x8*)&As[cur][wr * 64 + mi * 16 + lm][lg * 8];
        #pragma unroll
        for (int ni = 0; ni < 4; ni++) bfr[ni] = *(const bf16x8*)&Bs[cur][wc * 64 + ni * 16 + lm][lg * 8];
        __builtin_amdgcn_s_setprio(1);
        #pragma unroll
        for (int mi = 0; mi < 4; mi++)
            #pragma unroll
            for (int ni = 0; ni < 4; ni++)
                acc[mi][ni] = __builtin_amdgcn_mfma_f32_16x16x32_bf16(af[mi], bfr[ni], acc[mi][ni], 0, 0, 0);
        __builtin_amdgcn_s_setprio(0);
        __syncthreads();
        cur ^= 1;
    }

    const int bb = rowStart >> 12;
    const int s0base = (rowStart & 4095) + wr * 64;
    const int col0 = nColBase + wc * 64;
    #pragma unroll
    for (int ni = 0; ni < 4; ni++) {
        const int col = col0 + ni * 16 + lm;
        const int h = col >> 6, d = col & 63;
        const float bsv = bias[col];
        #pragma unroll
        for (int mi = 0; mi < 4; mi++) {
            const int srow = s0base + mi * 16 + lg * 4;
            if (mat == 2) {
                u16x4 pk;
                #pragma unroll
                for (int r = 0; r < 4; r++) pk[r] = f2bf(acc[mi][ni][r] + bsv);
                *(u16x4*)(vT + ((size_t)((bb * NHEAD + h) * HDIM + d)) * SEQ + srow) = pk;
            } else {
                u16* dst = (mat == 0) ? qo : ko;
                // q: 1/8 (Longformer scale) * log2(e) (exp2 softmax)
                const float scl = (mat == 0) ? 0.18033688011112042f : 1.f;
                #pragma unroll
                for (int r = 0; r < 4; r++)
                    dst[((size_t)(bb * NHEAD + h) * SEQ + srow + r) * HDIM + d] =
                        f2bf((acc[mi][ni][r] + bsv) * scl);
            }
        }
    }
}

// ---------------------------------------------------------------------------
// MFMA flash attention, swapped-operand form.
// QK^T: mfma(K,Q) -> S^T[key][q]; each thread owns q=lm (scalar m,l).
// PV:   mfma(V^T,P^T) -> O^T[d][q]; rescale factor is thread-scalar.
// LDS = 40KB exactly -> 4 blocks/CU. XCD-chunked swizzle for K/V L2 reuse.
// ---------------------------------------------------------------------------
__global__ __launch_bounds__(256, 4) void attn_mfma(
    const u16* __restrict__ Q, const u16* __restrict__ K,
    const u16* __restrict__ vT, const float* __restrict__ amask,
    float* __restrict__ out)
{
    __shared__ u16 Ks[2][64][64];     // [key][d], chunk^=(key&7)
    __shared__ u16 Vs[2][64][64];     // [d][key], chunk^=(d&7)
    __shared__ u16 Pl[4][16][64];     // per-wave P[q][k], chunk^=(q&7)

    const int t  = threadIdx.x;
    const int wv = t >> 6, ln = t & 63, lg = ln >> 4, lm = ln & 15;
    const int lm7 = lm & 7;

    // XCD-chunked swizzle: 1536 blocks; XCD c gets 3 full (b,h) panels
    const int id  = blockIdx.x + 64 * (blockIdx.y + 12 * blockIdx.z);
    const int nid = (id & 7) * 192 + (id >> 3);
    const int qtile = nid & 63;
    const int hb = nid >> 6;
    const int h = hb % NHEAD, b = hb / NHEAD;

    const int qb0 = qtile * 64;
    const size_t bh = (size_t)(b * NHEAD + h);
    const size_t bS = (size_t)b * SEQ;

    // Q fragments straight to regs (B-operand: lane holds Q[q=lm][d=lg*8..+8])
    const int qrow = qb0 + wv * 16 + lm;
    const bf16x8 qa0 = *(const bf16x8*)(Q + (bh * SEQ + qrow) * HDIM + lg * 8);
    const bf16x8 qa1 = *(const bf16x8*)(Q + (bh * SEQ + qrow) * HDIM + 32 + lg * 8);

    f32x4 po[4];
    #pragma unroll
    for (int i = 0; i < 4; i++) po[i] = (f32x4){0.f, 0.f, 0.f, 0.f};
    float mrun = -1e9f, lrun = 0.f;

    const int tlo = (4 - qtile) > 0 ? (4 - qtile) : 0;
    const int thi_raw = (SEQ + 192 - qb0) >> 6;
    const int thi = thi_raw < 8 ? thi_raw : 8;

    u16x8 kreg[2], vreg[2];

    auto load_regs = [&](int tt) {
        const int jt0 = qb0 - WIN + tt * 64;
        #pragma unroll
        for (int i = 0; i < 2; i++) {
            int cid = t + i * 256;
            int row = cid >> 3, c = cid & 7;
            kreg[i] = *(const u16x8*)(K  + (bh * SEQ + jt0 + row) * HDIM + c * 8);
            vreg[i] = *(const u16x8*)(vT + (bh * HDIM + row) * SEQ + jt0 + c * 8);
        }
    };
    auto write_lds = [&](int buf) {
        #pragma unroll
        for (int i = 0; i < 2; i++) {
            int cid = t + i * 256;
            int row = cid >> 3, c = cid & 7;
            *(u16x8*)&Ks[buf][row][(c ^ (row & 7)) * 8] = kreg[i];
            *(u16x8*)&Vs[buf][row][(c ^ (row & 7)) * 8] = vreg[i];
        }
    };

    load_regs(tlo);
    write_lds(0);
    __syncthreads();
    int cur = 0;

    for (int tt = tlo; tt <= thi; ++tt) {
        const int jt0 = qb0 - WIN + tt * 64;
        const float kmv = amask[bS + jt0 + ln];    // key mask, lane ln -> key jt0+ln
        if (tt < thi) load_regs(tt + 1);

        // ---- S^T = K . Q^T : sv[jf][r] = S[key=jt0+jf*16+lg*4+r][q=lm] ----
        f32x4 sv[4];
        #pragma unroll
        for (int jf = 0; jf < 4; jf++) sv[jf] = (f32x4){0.f, 0.f, 0.f, 0.f};
        __builtin_amdgcn_s_setprio(1);
        #pragma unroll
        for (int jf = 0; jf < 4; jf++) {
            const u16* kr = &Ks[cur][jf * 16 + lm][0];
            bf16x8 kb0 = *(const bf16x8*)(kr + ((lg ^ lm7) << 3));
            bf16x8 kb1 = *(const bf16x8*)(kr + (((4 + lg) ^ lm7) << 3));
            sv[jf] = __builtin_amdgcn_mfma_f32_16x16x32_bf16(kb0, qa0, sv[jf], 0, 0, 0);
            sv[jf] = __builtin_amdgcn_mfma_f32_16x16x32_bf16(kb1, qa1, sv[jf], 0, 0, 0);
        }
        __builtin_amdgcn_s_setprio(0);

        const bool anym = (__ballot(kmv < 0.f) != 0ULL);
        const bool fastp = (tt >= 1) && (tt <= 7) && !anym;
        if (!fastp) {
            #pragma unroll
            for (int jf = 0; jf < 4; jf++)
                #pragma unroll
                for (int r = 0; r < 4; r++) {
                    const int j = jt0 + jf * 16 + lg * 4 + r;
                    const float km = __shfl(kmv, jf * 16 + lg * 4 + r);
                    const int rel = j - qrow;
                    const bool ok = (rel <= WIN) && (rel >= -WIN) && (km >= 0.f);
                    sv[jf][r] = ok ? sv[jf][r] : -1e9f;
                }
        }

        // ---- online softmax: thread-scalar m,l for q=lm ----
        f32x4 mv = sv[0];
        #pragma unroll
        for (int jf = 1; jf < 4; jf++) {
            mv[0] = fmaxf(mv[0], sv[jf][0]); mv[1] = fmaxf(mv[1], sv[jf][1]);
            mv[2] = fmaxf(mv[2], sv[jf][2]); mv[3] = fmaxf(mv[3], sv[jf][3]);
        }
        float mx = fmaxf(fmaxf(mv[0], mv[1]), fmaxf(mv[2], mv[3]));
        mx = fmaxf(mx, __shfl_xor(mx, 16));
        mx = fmaxf(mx, __shfl_xor(mx, 32));
        const float mnew = fmaxf(mrun, mx);
        const float f = exp2f(mrun - mnew);
        mrun = mnew;

        float p[4][4];
        if (fastp) {
            #pragma unroll
            for (int jf = 0; jf < 4; jf++)
                #pragma unroll
                for (int r = 0; r < 4; r++) p[jf][r] = exp2f(sv[jf][r] - mnew);
        } else {
            #pragma unroll
            for (int jf = 0; jf < 4; jf++)
                #pragma unroll
                for (int r = 0; r < 4; r++)
                    p[jf][r] = sv[jf][r] > -1e8f ? exp2f(sv[jf][r] - mnew) : 0.f;
        }

        float ps = 0.f;
        #pragma unroll
        for (int jf = 0; jf < 4; jf++)
            ps += (p[jf][0] + p[jf][1]) + (p[jf][2] + p[jf][3]);
        ps += __shfl_xor(ps, 16);
        ps += __shfl_xor(ps, 32);
        lrun = lrun * f + ps;

        // ---- pack P -> LDS (row q=lm, k-pairs are cvt_pk-adjacent) ----
        u32* prow = (u32*)&Pl[wv][lm][0];
        #pragma unroll
        for (int jf = 0; jf < 4; jf++) {
            u32 lo, hi;
            asm("v_cvt_pk_bf16_f32 %0, %1, %2" : "=v"(lo) : "v"(p[jf][0]), "v"(p[jf][1]));
            asm("v_cvt_pk_bf16_f32 %0, %1, %2" : "=v"(hi) : "v"(p[jf][2]), "v"(p[jf][3]));
            const int c = 2 * jf + (lg >> 1);
            u32x2 val; val[0] = lo; val[1] = hi;
            *(u32x2*)(prow + ((c ^ lm7) << 2) + ((lg & 1) << 1)) = val;
        }
        asm volatile("" ::: "memory");   // P writes before P reads (same wave)

        po[0] *= f; po[1] *= f; po[2] *= f; po[3] *= f;

        // ---- O^T += V^T . P^T ----
        const u16* pw = &Pl[wv][lm][0];
        const bf16x8 pa0 = *(const bf16x8*)(pw + ((lg ^ lm7) << 3));
        const bf16x8 pa1 = *(const bf16x8*)(pw + (((4 + lg) ^ lm7) << 3));
        __builtin_amdgcn_s_setprio(1);
        #pragma unroll
        for (int df = 0; df < 4; df++) {
            const u16* vr = &Vs[cur][df * 16 + lm][0];
            bf16x8 va0 = *(const bf16x8*)(vr + ((lg ^ lm7) << 3));
            bf16x8 va1 = *(const bf16x8*)(vr + (((4 + lg) ^ lm7) << 3));
            po[df] = __builtin_amdgcn_mfma_f32_16x16x32_bf16(va0, pa0, po[df], 0, 0, 0);
            po[df] = __builtin_amdgcn_mfma_f32_16x16x32_bf16(va1, pa1, po[df], 0, 0, 0);
        }
        __builtin_amdgcn_s_setprio(0);

        if (tt < thi) write_lds(cur ^ 1);
        __syncthreads();
        cur ^= 1;
    }

    // ---- epilogue: O[q=lm][d=df*16+lg*4+r], f32x4 stores ----
    const float qm = amask[bS + qrow];
    const float inv = (lrun > 0.f && qm >= 0.f) ? 1.f / lrun : 0.f;
    float* op = out + (bS + qrow) * DM + h * HDIM;
    #pragma unroll
    for (int df = 0; df < 4; df++) {
        f32x4 o = po[df] * inv;
        *(f32x4*)(op + df * 16 + lg * 4) = o;
    }
}

extern "C" void kernel_launch(void* const* d_in, const int* in_sizes, int n_in,
                              void* d_out, int out_size, void* d_ws, size_t ws_size,
                              hipStream_t stream) {
    const float* hs    = (const float*)d_in[0];
    const float* amask = (const float*)d_in[1];
    const float* Wq    = (const float*)d_in[2];
    const float* bq    = (const float*)d_in[3];
    const float* Wk    = (const float*)d_in[4];
    const float* bk    = (const float*)d_in[5];
    const float* Wv    = (const float*)d_in[6];
    const float* bv    = (const float*)d_in[7];

    const size_t nA   = (size_t)BATCH * SEQ * DM;
    const size_t nW   = (size_t)3 * DM * DM;
    const size_t nQKV = (size_t)BATCH * NHEAD * SEQ * HDIM;

    u16* Abf = (u16*)d_ws;
    u16* Wt  = Abf + nA;
    u16* qb  = Wt + nW;
    u16* kb  = qb + nQKV;
    u16* vT  = kb + nQKV;

    prep<<<4800, 256, 0, stream>>>(hs, Abf, Wq, Wk, Wv, Wt);
    qkv_mfma<<<dim3(3 * DM / 128, BATCH * SEQ / 128), 256, 0, stream>>>(
        Abf, Wt, bq, bk, bv, qb, kb, vT);
    attn_mfma<<<dim3(SEQ / 64, NHEAD, BATCH), 256, 0, stream>>>(
        qb, kb, vT, amask, (float*)d_out);
}

// Round 6
// 94.308 us; speedup vs baseline: 10.9631x; 1.0833x over previous
//
#include <hip/hip_runtime.h>
#include <hip/hip_bf16.h>

#define BATCH 2
#define SEQ   4096
#define DM    768
#define NHEAD 12
#define HDIM  64
#define WIN   256

typedef unsigned short u16;
typedef unsigned int u32;
typedef __attribute__((ext_vector_type(8))) short bf16x8;
typedef __attribute__((ext_vector_type(4))) float f32x4;
typedef __attribute__((ext_vector_type(8))) unsigned short u16x8;
typedef __attribute__((ext_vector_type(4))) unsigned short u16x4;
typedef __attribute__((ext_vector_type(2))) unsigned int u32x2;

__device__ __forceinline__ u16 f2bf(float x) {
    unsigned u = __builtin_bit_cast(unsigned, x);
    return (u16)((u + 0x7FFFu + ((u >> 16) & 1u)) >> 16);
}

// async global->LDS, 16B per lane; LDS dest must be wave-uniform base + lane*16
#define GLL16(g, l) __builtin_amdgcn_global_load_lds( \
    (const __attribute__((address_space(1))) u32*)(g), \
    (__attribute__((address_space(3))) u32*)(l), 16, 0, 0)

// ---------------------------------------------------------------------------
// prep: [blocks 0..3071] hidden fp32 -> bf16 ; [3072..4799] W -> Wt[mat][n][k]
// ---------------------------------------------------------------------------
__global__ __launch_bounds__(256) void prep(
    const float* __restrict__ in, u16* __restrict__ Abf,
    const float* __restrict__ Wq, const float* __restrict__ Wk,
    const float* __restrict__ Wv, u16* __restrict__ Wt)
{
    __shared__ float tile[32][33];
    const int bid = blockIdx.x;
    if (bid < 3072) {
        size_t i = ((size_t)bid * 256 + threadIdx.x) * 8;
        float4 a = *(const float4*)(in + i);
        float4 b = *(const float4*)(in + i + 4);
        u16x8 r;
        r[0] = f2bf(a.x); r[1] = f2bf(a.y); r[2] = f2bf(a.z); r[3] = f2bf(a.w);
        r[4] = f2bf(b.x); r[5] = f2bf(b.y); r[6] = f2bf(b.z); r[7] = f2bf(b.w);
        *(u16x8*)(Abf + i) = r;
    } else {
        const int wb = bid - 3072;
        const int mat = wb / 576;
        const int rem = wb - mat * 576;
        const int k0 = (rem / 24) * 32, n0 = (rem % 24) * 32;
        const float* W = (mat == 0) ? Wq : (mat == 1) ? Wk : Wv;
        const int tx = threadIdx.x & 31, ty = threadIdx.x >> 5;
        #pragma unroll
        for (int i = 0; i < 32; i += 8)
            tile[ty + i][tx] = W[(size_t)(k0 + ty + i) * DM + n0 + tx];
        __syncthreads();
        #pragma unroll
        for (int i = 0; i < 32; i += 8)
            Wt[(size_t)mat * DM * DM + (size_t)(n0 + ty + i) * DM + k0 + tx] = f2bf(tile[tx][ty + i]);
    }
}

// ---------------------------------------------------------------------------
// Fused QKV GEMM: 128x128 tile, BK=32, 3-buffer global_load_lds pipeline with
// counted vmcnt(4) + raw s_barrier (2 stages in flight), row-pair chunk-XOR
// LDS swizzle (conflict-free ds_read_b128; inverse swizzle on global source,
// LDS dest linear). XCD-chunked block swizzle.
// q scaled by (1/8)*log2(e) so attn uses exp2.
// ---------------------------------------------------------------------------
__global__ __launch_bounds__(256) void qkv_mfma(
    const u16* __restrict__ Abf, const u16* __restrict__ Wt,
    const float* __restrict__ bq, const float* __restrict__ bk, const float* __restrict__ bv,
    u16* __restrict__ qo, u16* __restrict__ ko, u16* __restrict__ vT)
{
    // 3 buffers x (A 8KB + B 8KB) = 48KB -> 3 blocks/CU
    __shared__ u16 lds[3 * 8192];

    const int t  = threadIdx.x;
    const int wv = t >> 6, ln = t & 63, lg = ln >> 4, lm = ln & 15;
    const int wr = wv >> 1, wc = wv & 1;

    // XCD-chunked swizzle: 1152 blocks, XCD c gets row-stripes [c*8, c*8+8)
    const int id  = blockIdx.x + 18 * blockIdx.y;
    const int nid = (id & 7) * 144 + (id >> 3);
    const int bx  = nid % 18, by = nid / 18;

    const int rowStart = by * 128;
    const int nG = bx * 128;
    const int mat = nG / DM;
    const int nColBase = nG - mat * DM;
    const float* bias = (mat == 0) ? bq : (mat == 1) ? bk : bv;
    const u16* Wm = Wt + (size_t)mat * DM * DM;

    f32x4 acc[4][4];
    #pragma unroll
    for (int i = 0; i < 4; i++)
        #pragma unroll
        for (int j = 0; j < 4; j++) acc[i][j] = (f32x4){0.f, 0.f, 0.f, 0.f};

    // ---- staging: decode linear LDS slot -> (row, k-chunk) via inverse swizzle
    // LDS byte (within 8KB region) = rp*128 + slot*16 ; slot = cfull ^ (rp&7),
    // cfull = (row&1)*4 + chunk  (row-pair = 128B = 8 chunks of 16B)
    int r0, c0, r1, c1;
    {
        int byte0 = t * 16;            // call 0: bytes [0,4096)
        int rp = byte0 >> 7, s = (byte0 >> 4) & 7, cf = s ^ (rp & 7);
        r0 = 2 * rp + (cf >> 2); c0 = cf & 3;
        int byte1 = 4096 + t * 16;     // call 1: bytes [4096,8192)
        rp = byte1 >> 7; s = (byte1 >> 4) & 7; cf = s ^ (rp & 7);
        r1 = 2 * rp + (cf >> 2); c1 = cf & 3;
    }
    const u16* gA0 = Abf + (size_t)(rowStart + r0) * DM + c0 * 8;
    const u16* gA1 = Abf + (size_t)(rowStart + r1) * DM + c1 * 8;
    const u16* gB0 = Wm  + (size_t)(nColBase + r0) * DM + c0 * 8;
    const u16* gB1 = Wm  + (size_t)(nColBase + r1) * DM + c1 * 8;

    auto STAGE = [&](int buf, int k0) {
        u16* base = lds + buf * 8192 + t * 8;   // linear dest, lane*16B
        GLL16(gA0 + k0, base);
        GLL16(gA1 + k0, base + 2048);
        GLL16(gB0 + k0, base + 4096);
        GLL16(gB1 + k0, base + 6144);
    };

    // swizzled read offset (u16 units) for (row, chunk lgc) within a region
    auto SWO = [&](int row, int lgc) -> int {
        return ((row >> 1) << 6) + (((((row & 1) << 2) + lgc) ^ ((row >> 1) & 7)) << 3);
    };

    auto COMPUTE = [&](int buf) {
        const u16* Ab = lds + buf * 8192;
        const u16* Bb = Ab + 4096;
        bf16x8 af[4], bfr[4];
        #pragma unroll
        for (int mi = 0; mi < 4; mi++) af[mi]  = *(const bf16x8*)(Ab + SWO(wr * 64 + mi * 16 + lm, lg));
        #pragma unroll
        for (int ni = 0; ni < 4; ni++) bfr[ni] = *(const bf16x8*)(Bb + SWO(wc * 64 + ni * 16 + lm, lg));
        __builtin_amdgcn_s_setprio(1);
        #pragma unroll
        for (int mi = 0; mi < 4; mi++)
            #pragma unroll
            for (int ni = 0; ni < 4; ni++)
                acc[mi][ni] = __builtin_amdgcn_mfma_f32_16x16x32_bf16(af[mi], bfr[ni], acc[mi][ni], 0, 0, 0);
        __builtin_amdgcn_s_setprio(0);
    };

    STAGE(0, 0);
    STAGE(1, 32);
    int cur = 0;
    for (int it = 0; it < 23; ++it) {
        asm volatile("s_waitcnt vmcnt(4)" ::: "memory");   // buf cur's 4 loads done
        __builtin_amdgcn_s_barrier();
        if (it < 22) {
            int nb = cur + 2; if (nb >= 3) nb -= 3;
            STAGE(nb, (it + 2) * 32);
        }
        COMPUTE(cur);
        cur = (cur == 2) ? 0 : cur + 1;
    }
    asm volatile("s_waitcnt vmcnt(0)" ::: "memory");       // last stage done
    __builtin_amdgcn_s_barrier();
    COMPUTE(cur);

    const int bb = rowStart >> 12;
    const int s0base = (rowStart & 4095) + wr * 64;
    const int col0 = nColBase + wc * 64;
    #pragma unroll
    for (int ni = 0; ni < 4; ni++) {
        const int col = col0 + ni * 16 + lm;
        const int h = col >> 6, d = col & 63;
        const float bsv = bias[col];
        #pragma unroll
        for (int mi = 0; mi < 4; mi++) {
            const int srow = s0base + mi * 16 + lg * 4;
            if (mat == 2) {
                u16x4 pk;
                #pragma unroll
                for (int r = 0; r < 4; r++) pk[r] = f2bf(acc[mi][ni][r] + bsv);
                *(u16x4*)(vT + ((size_t)((bb * NHEAD + h) * HDIM + d)) * SEQ + srow) = pk;
            } else {
                u16* dst = (mat == 0) ? qo : ko;
                // q: 1/8 (Longformer scale) * log2(e) (exp2 softmax)
                const float scl = (mat == 0) ? 0.18033688011112042f : 1.f;
                #pragma unroll
                for (int r = 0; r < 4; r++)
                    dst[((size_t)(bb * NHEAD + h) * SEQ + srow + r) * HDIM + d] =
                        f2bf((acc[mi][ni][r] + bsv) * scl);
            }
        }
    }
}

// ---------------------------------------------------------------------------
// MFMA flash attention, swapped-operand form.
// QK^T: mfma(K,Q) -> S^T[key][q]; each thread owns q=lm (scalar m,l).
// PV:   mfma(V^T,P^T) -> O^T[d][q]; rescale factor is thread-scalar.
// LDS = 40KB exactly -> 4 blocks/CU. XCD-chunked swizzle for K/V L2 reuse.
// ---------------------------------------------------------------------------
__global__ __launch_bounds__(256, 4) void attn_mfma(
    const u16* __restrict__ Q, const u16* __restrict__ K,
    const u16* __restrict__ vT, const float* __restrict__ amask,
    float* __restrict__ out)
{
    __shared__ u16 Ks[2][64][64];     // [key][d], chunk^=(key&7)
    __shared__ u16 Vs[2][64][64];     // [d][key], chunk^=(d&7)
    __shared__ u16 Pl[4][16][64];     // per-wave P[q][k], chunk^=(q&7)

    const int t  = threadIdx.x;
    const int wv = t >> 6, ln = t & 63, lg = ln >> 4, lm = ln & 15;
    const int lm7 = lm & 7;

    // XCD-chunked swizzle: 1536 blocks; XCD c gets 3 full (b,h) panels
    const int id  = blockIdx.x + 64 * (blockIdx.y + 12 * blockIdx.z);
    const int nid = (id & 7) * 192 + (id >> 3);
    const int qtile = nid & 63;
    const int hb = nid >> 6;
    const int h = hb % NHEAD, b = hb / NHEAD;

    const int qb0 = qtile * 64;
    const size_t bh = (size_t)(b * NHEAD + h);
    const size_t bS = (size_t)b * SEQ;

    // Q fragments straight to regs (B-operand: lane holds Q[q=lm][d=lg*8..+8])
    const int qrow = qb0 + wv * 16 + lm;
    const bf16x8 qa0 = *(const bf16x8*)(Q + (bh * SEQ + qrow) * HDIM + lg * 8);
    const bf16x8 qa1 = *(const bf16x8*)(Q + (bh * SEQ + qrow) * HDIM + 32 + lg * 8);

    f32x4 po[4];
    #pragma unroll
    for (int i = 0; i < 4; i++) po[i] = (f32x4){0.f, 0.f, 0.f, 0.f};
    float mrun = -1e9f, lrun = 0.f;

    const int tlo = (4 - qtile) > 0 ? (4 - qtile) : 0;
    const int thi_raw = (SEQ + 192 - qb0) >> 6;
    const int thi = thi_raw < 8 ? thi_raw : 8;

    u16x8 kreg[2], vreg[2];

    auto load_regs = [&](int tt) {
        const int jt0 = qb0 - WIN + tt * 64;
        #pragma unroll
        for (int i = 0; i < 2; i++) {
            int cid = t + i * 256;
            int row = cid >> 3, c = cid & 7;
            kreg[i] = *(const u16x8*)(K  + (bh * SEQ + jt0 + row) * HDIM + c * 8);
            vreg[i] = *(const u16x8*)(vT + (bh * HDIM + row) * SEQ + jt0 + c * 8);
        }
    };
    auto write_lds = [&](int buf) {
        #pragma unroll
        for (int i = 0; i < 2; i++) {
            int cid = t + i * 256;
            int row = cid >> 3, c = cid & 7;
            *(u16x8*)&Ks[buf][row][(c ^ (row & 7)) * 8] = kreg[i];
            *(u16x8*)&Vs[buf][row][(c ^ (row & 7)) * 8] = vreg[i];
        }
    };

    load_regs(tlo);
    write_lds(0);
    __syncthreads();
    int cur = 0;

    for (int tt = tlo; tt <= thi; ++tt) {
        const int jt0 = qb0 - WIN + tt * 64;
        const float kmv = amask[bS + jt0 + ln];    // key mask, lane ln -> key jt0+ln
        if (tt < thi) load_regs(tt + 1);

        // ---- S^T = K . Q^T : sv[jf][r] = S[key=jt0+jf*16+lg*4+r][q=lm] ----
        f32x4 sv[4];
        #pragma unroll
        for (int jf = 0; jf < 4; jf++) sv[jf] = (f32x4){0.f, 0.f, 0.f, 0.f};
        __builtin_amdgcn_s_setprio(1);
        #pragma unroll
        for (int jf = 0; jf < 4; jf++) {
            const u16* kr = &Ks[cur][jf * 16 + lm][0];
            bf16x8 kb0 = *(const bf16x8*)(kr + ((lg ^ lm7) << 3));
            bf16x8 kb1 = *(const bf16x8*)(kr + (((4 + lg) ^ lm7) << 3));
            sv[jf] = __builtin_amdgcn_mfma_f32_16x16x32_bf16(kb0, qa0, sv[jf], 0, 0, 0);
            sv[jf] = __builtin_amdgcn_mfma_f32_16x16x32_bf16(kb1, qa1, sv[jf], 0, 0, 0);
        }
        __builtin_amdgcn_s_setprio(0);

        const bool anym = (__ballot(kmv < 0.f) != 0ULL);
        const bool fastp = (tt >= 1) && (tt <= 7) && !anym;
        if (!fastp) {
            #pragma unroll
            for (int jf = 0; jf < 4; jf++)
                #pragma unroll
                for (int r = 0; r < 4; r++) {
                    const int j = jt0 + jf * 16 + lg * 4 + r;
                    const float km = __shfl(kmv, jf * 16 + lg * 4 + r);
                    const int rel = j - qrow;
                    const bool ok = (rel <= WIN) && (rel >= -WIN) && (km >= 0.f);
                    sv[jf][r] = ok ? sv[jf][r] : -1e9f;
                }
        }

        // ---- online softmax: thread-scalar m,l for q=lm ----
        f32x4 mv = sv[0];
        #pragma unroll
        for (int jf = 1; jf < 4; jf++) {
            mv[0] = fmaxf(mv[0], sv[jf][0]); mv[1] = fmaxf(mv[1], sv[jf][1]);
            mv[2] = fmaxf(mv[2], sv[jf][2]); mv[3] = fmaxf(mv[3], sv[jf][3]);
        }
        float mx = fmaxf(fmaxf(mv[0], mv[1]), fmaxf(mv[2], mv[3]));
        mx = fmaxf(mx, __shfl_xor(mx, 16));
        mx = fmaxf(mx, __shfl_xor(mx, 32));
        const float mnew = fmaxf(mrun, mx);
        const float f = exp2f(mrun - mnew);
        mrun = mnew;

        float p[4][4];
        if (fastp) {
            #pragma unroll
            for (int jf = 0; jf < 4; jf++)
                #pragma unroll
                for (int r = 0; r < 4; r++) p[jf][r] = exp2f(sv[jf][r] - mnew);
        } else {
            #pragma unroll
            for (int jf = 0; jf < 4; jf++)
                #pragma unroll
                for (int r = 0; r < 4; r++)
                    p[jf][r] = sv[jf][r] > -1e8f ? exp2f(sv[jf][r] - mnew) : 0.f;
        }

        float ps = 0.f;
        #pragma unroll
        for (int jf = 0; jf < 4; jf++)
            ps += (p[jf][0] + p[jf][1]) + (p[jf][2] + p[jf][3]);
        ps += __shfl_xor(ps, 16);
        ps += __shfl_xor(ps, 32);
        lrun = lrun * f + ps;

        // ---- pack P -> LDS (row q=lm, k-pairs are cvt_pk-adjacent) ----
        u32* prow = (u32*)&Pl[wv][lm][0];
        #pragma unroll
        for (int jf = 0; jf < 4; jf++) {
            u32 lo, hi;
            asm("v_cvt_pk_bf16_f32 %0, %1, %2" : "=v"(lo) : "v"(p[jf][0]), "v"(p[jf][1]));
            asm("v_cvt_pk_bf16_f32 %0, %1, %2" : "=v"(hi) : "v"(p[jf][2]), "v"(p[jf][3]));
            const int c = 2 * jf + (lg >> 1);
            u32x2 val; val[0] = lo; val[1] = hi;
            *(u32x2*)(prow + ((c ^ lm7) << 2) + ((lg & 1) << 1)) = val;
        }
        asm volatile("" ::: "memory");   // P writes before P reads (same wave)

        po[0] *= f; po[1] *= f; po[2] *= f; po[3] *= f;

        // ---- O^T += V^T . P^T ----
        const u16* pw = &Pl[wv][lm][0];
        const bf16x8 pa0 = *(const bf16x8*)(pw + ((lg ^ lm7) << 3));
        const bf16x8 pa1 = *(const bf16x8*)(pw + (((4 + lg) ^ lm7) << 3));
        __builtin_amdgcn_s_setprio(1);
        #pragma unroll
        for (int df = 0; df < 4; df++) {
            const u16* vr = &Vs[cur][df * 16 + lm][0];
            bf16x8 va0 = *(const bf16x8*)(vr + ((lg ^ lm7) << 3));
            bf16x8 va1 = *(const bf16x8*)(vr + (((4 + lg) ^ lm7) << 3));
            po[df] = __builtin_amdgcn_mfma_f32_16x16x32_bf16(va0, pa0, po[df], 0, 0, 0);
            po[df] = __builtin_amdgcn_mfma_f32_16x16x32_bf16(va1, pa1, po[df], 0, 0, 0);
        }
        __builtin_amdgcn_s_setprio(0);

        if (tt < thi) write_lds(cur ^ 1);
        __syncthreads();
        cur ^= 1;
    }

    // ---- epilogue: O[q=lm][d=df*16+lg*4+r], f32x4 stores ----
    const float qm = amask[bS + qrow];
    const float inv = (lrun > 0.f && qm >= 0.f) ? 1.f / lrun : 0.f;
    float* op = out + (bS + qrow) * DM + h * HDIM;
    #pragma unroll
    for (int df = 0; df < 4; df++) {
        f32x4 o = po[df] * inv;
        *(f32x4*)(op + df * 16 + lg * 4) = o;
    }
}

extern "C" void kernel_launch(void* const* d_in, const int* in_sizes, int n_in,
                              void* d_out, int out_size, void* d_ws, size_t ws_size,
                              hipStream_t stream) {
    const float* hs    = (const float*)d_in[0];
    const float* amask = (const float*)d_in[1];
    const float* Wq    = (const float*)d_in[2];
    const float* bq    = (const float*)d_in[3];
    const float* Wk    = (const float*)d_in[4];
    const float* bk    = (const float*)d_in[5];
    const float* Wv    = (const float*)d_in[6];
    const float* bv    = (const float*)d_in[7];

    const size_t nA   = (size_t)BATCH * SEQ * DM;
    const size_t nW   = (size_t)3 * DM * DM;
    const size_t nQKV = (size_t)BATCH * NHEAD * SEQ * HDIM;

    u16* Abf = (u16*)d_ws;
    u16* Wt  = Abf + nA;
    u16* qb  = Wt + nW;
    u16* kb  = qb + nQKV;
    u16* vT  = kb + nQKV;

    prep<<<4800, 256, 0, stream>>>(hs, Abf, Wq, Wk, Wv, Wt);
    qkv_mfma<<<dim3(3 * DM / 128, BATCH * SEQ / 128), 256, 0, stream>>>(
        Abf, Wt, bq, bk, bv, qb, kb, vT);
    attn_mfma<<<dim3(SEQ / 64, NHEAD, BATCH), 256, 0, stream>>>(
        qb, kb, vT, amask, (float*)d_out);
}